// Round 1
// baseline (2155.663 us; speedup 1.0000x reference)
//
#include <hip/hip_runtime.h>

#define NN   50000
#define HID  256
#define PJ   1024          // HID * HEADS
#define FN   50000.0f
#define GCH  2048
#define GNCH 25

__device__ inline float wave_reduce(float v){
  #pragma unroll
  for(int o=32;o>0;o>>=1) v += __shfl_down(v,o,64);
  return v;
}

// all-threads block reduction (blockDim=256), sh4 is __shared__ float[4]
__device__ inline float block_reduce(float v, float* sh4){
  v = wave_reduce(v);
  int lane = threadIdx.x & 63, wv = threadIdx.x >> 6;
  if(lane==0) sh4[wv] = v;
  __syncthreads();
  float r = sh4[0]+sh4[1]+sh4[2]+sh4[3];
  __syncthreads();
  return r;
}

// ---------------------------------------------------------------- generic GEMM
// C[M,N] = A[M,K] @ B[K,N] (+bias). N%64==0, K%32==0. 64x64 tile, 256 thr.
__global__ void gemm_bias(const float* __restrict__ A, const float* __restrict__ B,
                          const float* __restrict__ bias, float* __restrict__ C,
                          int M, int N, int K){
  __shared__ float As[64][33];
  __shared__ float Bs[32][64];
  int bm = blockIdx.x*64, bn = blockIdx.y*64;
  int t = threadIdx.x;
  int tn = t & 15, tm = t >> 4;
  float acc[4][4] = {};
  for(int k0=0;k0<K;k0+=32){
    { int kk=t&31, rr=t>>5;
      #pragma unroll
      for(int p=0;p<8;p++){ int r=rr+p*8; int gm=bm+r;
        As[r][kk] = (gm<M) ? A[(size_t)gm*K + k0+kk] : 0.f; } }
    { int nn=t&63, kr=t>>6;
      #pragma unroll
      for(int p=0;p<8;p++){ int k=kr+p*4;
        Bs[k][nn] = B[(size_t)(k0+k)*N + bn+nn]; } }
    __syncthreads();
    for(int k=0;k<32;k++){
      float a[4], b[4];
      #pragma unroll
      for(int i=0;i<4;i++) a[i]=As[tm*4+i][k];
      #pragma unroll
      for(int j=0;j<4;j++) b[j]=Bs[k][tn*4+j];
      #pragma unroll
      for(int i=0;i<4;i++)
        #pragma unroll
        for(int j=0;j<4;j++) acc[i][j] += a[i]*b[j];
    }
    __syncthreads();
  }
  #pragma unroll
  for(int i=0;i<4;i++){
    int gm = bm + tm*4+i;
    if(gm>=M) continue;
    #pragma unroll
    for(int j=0;j<4;j++){
      int gn = bn + tn*4+j;
      float v = acc[i][j];
      if(bias) v += bias[gn];
      C[(size_t)gm*N + gn] = v;
    }
  }
}

// ------------------------------------------------------------ rowwise LN+ReLU
__global__ void ln_relu(const float* __restrict__ in, const float* __restrict__ g,
                        const float* __restrict__ b, float* __restrict__ out, int M){
  int lane = threadIdx.x & 63, wv = threadIdx.x >> 6;
  int row = blockIdx.x*4 + wv;
  if(row>=M) return;
  const float* r = in + (size_t)row*HID;
  float v[4], sum=0.f, sq=0.f;
  #pragma unroll
  for(int j=0;j<4;j++){ v[j]=r[lane+j*64]; sum+=v[j]; sq+=v[j]*v[j]; }
  sum = wave_reduce(sum); sq = wave_reduce(sq);
  sum = __shfl(sum,0,64); sq = __shfl(sq,0,64);
  float mu = sum*(1.f/HID);
  float var = sq*(1.f/HID) - mu*mu;
  float rs = rsqrtf(var + 1e-5f);
  #pragma unroll
  for(int j=0;j<4;j++){ int c=lane+j*64;
    float y = (v[j]-mu)*rs*g[c] + b[c];
    out[(size_t)row*HID + c] = fmaxf(y, 0.f); }
}

// ------------------------------------------------- G = h^T h  (split-K partials)
__global__ void gram_partial(const float* __restrict__ h, float* __restrict__ gp, int M){
  int ch = blockIdx.x, tile = blockIdx.y;
  int r0 = (tile>>2)*64, c0 = (tile&3)*64;
  int n0 = ch*GCH; int n1 = n0+GCH; if(n1>M) n1=M;
  __shared__ float As[32][64], Bs[32][64];
  int t=threadIdx.x, tn=t&15, tm=t>>4;
  float acc[4][4]={};
  for(int k0=n0;k0<n1;k0+=32){
    int kr=t>>6, cc=t&63;
    #pragma unroll
    for(int p=0;p<8;p++){
      int k=kr+p*4; int n=k0+k;
      float a=0.f, b=0.f;
      if(n<n1){ a = h[(size_t)n*HID + r0+cc]; b = h[(size_t)n*HID + c0+cc]; }
      As[k][cc]=a; Bs[k][cc]=b;
    }
    __syncthreads();
    for(int k=0;k<32;k++){
      float a[4], b[4];
      #pragma unroll
      for(int i=0;i<4;i++) a[i]=As[k][tm*4+i];
      #pragma unroll
      for(int j=0;j<4;j++) b[j]=Bs[k][tn*4+j];
      #pragma unroll
      for(int i=0;i<4;i++)
        #pragma unroll
        for(int j=0;j<4;j++) acc[i][j] += a[i]*b[j];
    }
    __syncthreads();
  }
  float* dst = gp + (size_t)ch*65536;
  #pragma unroll
  for(int i=0;i<4;i++)
    #pragma unroll
    for(int j=0;j<4;j++)
      dst[(r0+tm*4+i)*256 + c0+tn*4+j] = acc[i][j];
}

__global__ void gram_reduce(const float* __restrict__ gp, float* __restrict__ G){
  int i = blockIdx.x*256 + threadIdx.x;
  float s=0.f;
  for(int c=0;c<GNCH;c++) s += gp[(size_t)c*65536 + i];
  G[i]=s;
}

// ------------------------------------------------------------- s = colsum(h)
__global__ void colsum_partial(const float* __restrict__ h, float* __restrict__ cp, int M){
  int col = threadIdx.x, ch = blockIdx.x;            // 128 chunks of 391 rows
  int n0 = ch*391; int n1 = n0+391; if(n1>M) n1=M;
  float s=0.f;
  for(int n=n0;n<n1;n++) s += h[(size_t)n*HID + col];
  cp[ch*256+col]=s;
}
__global__ void colsum_reduce(const float* __restrict__ cp, float* __restrict__ s){
  int col=threadIdx.x; float v=0.f;
  for(int c=0;c<128;c++) v += cp[c*256+col];
  s[col]=v;
}

// ------------------------------------------- a{q,k,v} = W^T s  (3 x 1024 outs)
__global__ void wt_s(const float* __restrict__ Wq, const float* __restrict__ Wk,
                     const float* __restrict__ Wv, const float* __restrict__ s,
                     float* __restrict__ avec){
  const float* Wsel = (blockIdx.x==0)?Wq:(blockIdx.x==1)?Wk:Wv;
  int col = blockIdx.y*256 + threadIdx.x;
  __shared__ float ss[256];
  ss[threadIdx.x]=s[threadIdx.x];
  __syncthreads();
  float acc=0.f;
  for(int i=0;i<256;i++) acc += Wsel[(size_t)i*PJ + col]*ss[i];
  avec[blockIdx.x*1024 + col]=acc;
}

// ------------------- trace terms: tq = sum(Wq .* GWq), tk = sum(Wk .* GWk)
__global__ void trace_partial(const float* __restrict__ Wq, const float* __restrict__ Wk,
                              const float* __restrict__ gw, float* __restrict__ trp){
  int which = blockIdx.x;
  const float* Wsel = which ? Wk : Wq;
  const float* GW = gw + (size_t)which*262144;
  int t=threadIdx.x;
  int base = blockIdx.y*4096 + t;
  float s=0.f;
  #pragma unroll
  for(int i=0;i<16;i++){ int idx=base+i*256; s += Wsel[idx]*GW[idx]; }
  __shared__ float sh4[4];
  float r = block_reduce(s, sh4);
  if(t==0) trp[which*64 + blockIdx.y] = r;
}

// ---------------- scalars: scale = 1/(|q||k|); ksum = ak + N*bk
__global__ void finalize_scalars(const float* __restrict__ trp, const float* __restrict__ bq,
                                 const float* __restrict__ bk, const float* __restrict__ avec,
                                 float* __restrict__ ksum, float* __restrict__ scal){
  __shared__ float sh4[4];
  int t=threadIdx.x;
  float pq = (t<64)? trp[t]    : 0.f;
  float pk = (t<64)? trp[64+t] : 0.f;
  float bqaq=0.f,bkak=0.f,bq2=0.f,bk2=0.f;
  #pragma unroll
  for(int p=0;p<4;p++){ int jn=t+p*256;
    float q=bq[jn], k=bk[jn];
    bqaq += q*avec[jn]; bkak += k*avec[1024+jn];
    bq2 += q*q; bk2 += k*k; }
  float tq = block_reduce(pq, sh4);
  float tk = block_reduce(pk, sh4);
  float s1 = block_reduce(bqaq, sh4);
  float s2 = block_reduce(bkak, sh4);
  float s3 = block_reduce(bq2, sh4);
  float s4 = block_reduce(bk2, sh4);
  if(t==0){
    float q2 = tq + 2.f*s1 + FN*s3;
    float k2 = tk + 2.f*s2 + FN*s4;
    scal[0] = rsqrtf(q2)*rsqrtf(k2);
  }
  #pragma unroll
  for(int p=0;p<4;p++){ int jn=t+p*256; ksum[jn] = avec[1024+jn] + FN*bk[jn]; }
}

// ------ kvs_h = Wk_h^T (G Wv)_h + ak_h (x) bv_h + bk_h (x) av_h + N bk_h (x) bv_h
__global__ void kvs_k(const float* __restrict__ Wk, const float* __restrict__ GWv,
                      const float* __restrict__ avec, const float* __restrict__ bk,
                      const float* __restrict__ bv, float* __restrict__ kvs){
  int hh=blockIdx.x, tile=blockIdx.y;
  int m0=(tile>>2)*64, d0=(tile&3)*64;
  __shared__ float As[32][64], Bs[32][64];
  int t=threadIdx.x, tn=t&15, tm=t>>4;
  float acc[4][4]={};
  for(int k0=0;k0<256;k0+=32){
    int kr=t>>6, cc=t&63;
    #pragma unroll
    for(int p=0;p<8;p++){
      int k=kr+p*4;
      As[k][cc] = Wk [(size_t)(k0+k)*PJ + hh*256 + m0+cc];
      Bs[k][cc] = GWv[(size_t)(k0+k)*PJ + hh*256 + d0+cc];
    }
    __syncthreads();
    for(int k=0;k<32;k++){
      float a[4], b[4];
      #pragma unroll
      for(int i=0;i<4;i++) a[i]=As[k][tm*4+i];
      #pragma unroll
      for(int j=0;j<4;j++) b[j]=Bs[k][tn*4+j];
      #pragma unroll
      for(int i=0;i<4;i++)
        #pragma unroll
        for(int j=0;j<4;j++) acc[i][j] += a[i]*b[j];
    }
    __syncthreads();
  }
  const float* ak = avec+1024; const float* av = avec+2048;
  #pragma unroll
  for(int i=0;i<4;i++)
    #pragma unroll
    for(int j=0;j<4;j++){
      int m=m0+tm*4+i, d=d0+tn*4+j;
      float akm=ak[hh*256+m], bkm=bk[hh*256+m];
      float avd=av[hh*256+d], bvd=bv[hh*256+d];
      kvs[(size_t)hh*65536 + m*256 + d] = acc[i][j] + akm*bvd + bkm*avd + FN*bkm*bvd;
    }
}

// -------- U_h = scale * Wq_h @ kvs_h + N * Wv_h   (stored like W: [256][1024])
__global__ void u_gemm(const float* __restrict__ Wq, const float* __restrict__ kvs,
                       const float* __restrict__ Wv, const float* __restrict__ scal,
                       float* __restrict__ U){
  int hh=blockIdx.x, tile=blockIdx.y;
  int i0=(tile>>2)*64, d0=(tile&3)*64;
  __shared__ float As[64][33]; __shared__ float Bs[32][64];
  int t=threadIdx.x, tn=t&15, tm=t>>4;
  float acc[4][4]={};
  for(int k0=0;k0<256;k0+=32){
    { int kk=t&31, rr=t>>5;
      #pragma unroll
      for(int p=0;p<8;p++){ int r=rr+p*8;
        As[r][kk] = Wq[(size_t)(i0+r)*PJ + hh*256 + k0+kk]; } }
    { int kr=t>>6, cc=t&63;
      #pragma unroll
      for(int p=0;p<8;p++){ int k=kr+p*4;
        Bs[k][cc] = kvs[(size_t)hh*65536 + (k0+k)*256 + d0+cc]; } }
    __syncthreads();
    for(int k=0;k<32;k++){
      float a[4], b[4];
      #pragma unroll
      for(int i=0;i<4;i++) a[i]=As[tm*4+i][k];
      #pragma unroll
      for(int j=0;j<4;j++) b[j]=Bs[k][tn*4+j];
      #pragma unroll
      for(int i=0;i<4;i++)
        #pragma unroll
        for(int j=0;j<4;j++) acc[i][j] += a[i]*b[j];
    }
    __syncthreads();
  }
  float sc = scal[0];
  #pragma unroll
  for(int i=0;i<4;i++)
    #pragma unroll
    for(int j=0;j<4;j++){
      int ii=i0+tm*4+i, d=d0+tn*4+j;
      size_t idx = (size_t)ii*PJ + hh*256 + d;
      U[idx] = sc*acc[i][j] + FN*Wv[idx];
    }
}

// ---- per-head vectors: u_h, wvec_h, c_h
__global__ void head_vecs(const float* __restrict__ Wq, const float* __restrict__ bq,
                          const float* __restrict__ bv, const float* __restrict__ kvs,
                          const float* __restrict__ ksum, const float* __restrict__ scal,
                          float* __restrict__ uvec, float* __restrict__ wvec,
                          float* __restrict__ cvec){
  int hh=blockIdx.x, t=threadIdx.x;
  float scale=scal[0];
  __shared__ float bqs[256], kss[256];
  __shared__ float sh4[4];
  bqs[t]=bq[hh*256+t]; kss[t]=ksum[hh*256+t];
  __syncthreads();
  float su=0.f;
  for(int m=0;m<256;m++) su += bqs[m]*kvs[(size_t)hh*65536 + m*256 + t];
  uvec[hh*256+t] = scale*su + FN*bv[hh*256+t];
  float sw=0.f;
  for(int m=0;m<256;m++) sw += Wq[(size_t)t*PJ + hh*256 + m]*kss[m];
  wvec[hh*256+t] = scale*sw;
  float pc = bqs[t]*kss[t];
  float total = block_reduce(pc, sh4);
  if(t==0) cvec[hh] = scale*total + FN;
}

// ---- denom[n][h] = h[n] . wvec_h + c_h
__global__ void denom_k(const float* __restrict__ h, const float* __restrict__ wvec,
                        const float* __restrict__ cvec, float* __restrict__ denom, int M){
  __shared__ float wvl[1024];
  for(int i=threadIdx.x;i<1024;i+=256) wvl[i]=wvec[i];
  __syncthreads();
  int lane=threadIdx.x&63, wv=threadIdx.x>>6;
  int row=blockIdx.x*4+wv;
  if(row>=M) return;
  float p[4]={0.f,0.f,0.f,0.f};
  #pragma unroll
  for(int j=0;j<4;j++){
    float hv = h[(size_t)row*HID + lane + j*64];
    #pragma unroll
    for(int hh=0;hh<4;hh++) p[hh] += hv*wvl[hh*256 + lane + j*64];
  }
  #pragma unroll
  for(int hh=0;hh<4;hh++) p[hh]=wave_reduce(p[hh]);
  if(lane==0){
    #pragma unroll
    for(int hh=0;hh<4;hh++) denom[(size_t)row*4+hh] = p[hh]+cvec[hh];
  }
}

// ---- fused: pre = h @ Ucat + ucat ; mean over heads of pre/denom ; residual
// block: 64 rows x 64 out-cols (x4 heads internally). out = (mean + h)/2 (pre-LN)
__global__ void attn_gemm(const float* __restrict__ h, const float* __restrict__ U,
                          const float* __restrict__ uvec, const float* __restrict__ denom,
                          float* __restrict__ out, int M){
  int bm = blockIdx.x*64, c0 = blockIdx.y*64;
  __shared__ float As[64][33];
  __shared__ float Bs[32][256];
  int t=threadIdx.x; int j=t&63, ty=t>>6;
  float acc[16][4]={};
  for(int k0=0;k0<HID;k0+=32){
    { int kk=t&31, rr=t>>5;
      #pragma unroll
      for(int p=0;p<8;p++){ int r=rr+p*8; int gm=bm+r;
        As[r][kk] = (gm<M)? h[(size_t)gm*HID + k0+kk] : 0.f; } }
    { int hh=t>>6, jj=t&63;
      #pragma unroll
      for(int kk=0;kk<32;kk++)
        Bs[kk][t] = U[(size_t)(k0+kk)*PJ + hh*256 + c0 + jj]; }
    __syncthreads();
    for(int kk=0;kk<32;kk++){
      float bv[4];
      #pragma unroll
      for(int hh=0;hh<4;hh++) bv[hh]=Bs[kk][hh*64+j];
      #pragma unroll
      for(int i=0;i<16;i++){
        float a = As[ty*16+i][kk];
        #pragma unroll
        for(int hh=0;hh<4;hh++) acc[i][hh] += a*bv[hh];
      }
    }
    __syncthreads();
  }
  float uv[4];
  #pragma unroll
  for(int hh=0;hh<4;hh++) uv[hh] = uvec[hh*256 + c0 + j];
  #pragma unroll
  for(int i=0;i<16;i++){
    int r = bm + ty*16 + i;
    if(r>=M) continue;
    float v = 0.f;
    #pragma unroll
    for(int hh=0;hh<4;hh++){
      float d = denom[(size_t)r*4+hh];
      v += (acc[i][hh] + uv[hh]) / d;
    }
    v *= 0.25f;
    float res = (v + h[(size_t)r*HID + c0 + j]) * 0.5f;
    out[(size_t)r*HID + c0 + j] = res;
  }
}

extern "C" void kernel_launch(void* const* d_in, const int* in_sizes, int n_in,
                              void* d_out, int out_size, void* d_ws, size_t ws_size,
                              hipStream_t stream){
  const float* x    = (const float*)d_in[0];
  const float* fc_w = (const float*)d_in[1];
  const float* fc_b = (const float*)d_in[2];
  const float* ln0g = (const float*)d_in[3];
  const float* ln0b = (const float*)d_in[4];
  float* out = (float*)d_out;

  float* W = (float*)d_ws;
  size_t o=0;
  float* buf0 = W+o; o+=(size_t)NN*HID;
  float* buf1 = W+o; o+=(size_t)NN*HID;
  float* G    = W+o; o+=65536;
  float* gramp= W+o; o+=(size_t)GNCH*65536;
  float* colp = W+o; o+=128*256;
  float* svec = W+o; o+=256;
  float* gw   = W+o; o+=3*262144;
  float* avec = W+o; o+=3072;
  float* trp  = W+o; o+=128;
  float* scal = W+o; o+=16;
  float* ksum = W+o; o+=1024;
  float* kvs  = W+o; o+=262144;
  float* Umat = W+o; o+=262144;
  float* uvec = W+o; o+=1024;
  float* wvec = W+o; o+=1024;
  float* cvec = W+o; o+=8;
  float* denB = W+o; o+=(size_t)NN*4;
  (void)ws_size; (void)in_sizes; (void)n_in; (void)out_size;

  dim3 blk(256);
  // input FFN: h = relu(LN(x @ fc_w + fc_b))
  gemm_bias<<<dim3(782,4),blk,0,stream>>>(x, fc_w, fc_b, buf0, NN, HID, 512);
  ln_relu<<<dim3(12500),blk,0,stream>>>(buf0, ln0g, ln0b, buf0, NN);

  for(int L=0; L<2; L++){
    const float* wq = (const float*)d_in[5+L*8+0];
    const float* bq = (const float*)d_in[5+L*8+1];
    const float* wk = (const float*)d_in[5+L*8+2];
    const float* bk = (const float*)d_in[5+L*8+3];
    const float* wv = (const float*)d_in[5+L*8+4];
    const float* bv = (const float*)d_in[5+L*8+5];
    const float* lng= (const float*)d_in[5+L*8+6];
    const float* lnb= (const float*)d_in[5+L*8+7];
    const float* hin = L ? buf1 : buf0;
    float* hpre = L ? buf0 : buf1;   // pre-LN result (residual applied)
    float* hout = L ? out  : buf1;   // post-LN destination

    gram_partial<<<dim3(GNCH,16),blk,0,stream>>>(hin, gramp, NN);
    gram_reduce<<<dim3(256),blk,0,stream>>>(gramp, G);
    colsum_partial<<<dim3(128),blk,0,stream>>>(hin, colp, NN);
    colsum_reduce<<<dim3(1),blk,0,stream>>>(colp, svec);
    gemm_bias<<<dim3(4,16),blk,0,stream>>>(G, wq, (const float*)nullptr, gw+0*262144, 256, PJ, 256);
    gemm_bias<<<dim3(4,16),blk,0,stream>>>(G, wk, (const float*)nullptr, gw+1*262144, 256, PJ, 256);
    gemm_bias<<<dim3(4,16),blk,0,stream>>>(G, wv, (const float*)nullptr, gw+2*262144, 256, PJ, 256);
    wt_s<<<dim3(3,4),blk,0,stream>>>(wq,wk,wv,svec,avec);
    trace_partial<<<dim3(2,64),blk,0,stream>>>(wq,wk,gw,trp);
    finalize_scalars<<<dim3(1),blk,0,stream>>>(trp,bq,bk,avec,ksum,scal);
    kvs_k<<<dim3(4,16),blk,0,stream>>>(wk, gw+2*262144, avec, bk, bv, kvs);
    u_gemm<<<dim3(4,16),blk,0,stream>>>(wq, kvs, wv, scal, Umat);
    head_vecs<<<dim3(4),blk,0,stream>>>(wq,bq,bv,kvs,ksum,scal,uvec,wvec,cvec);
    denom_k<<<dim3(12500),blk,0,stream>>>(hin, wvec, cvec, denB, NN);
    attn_gemm<<<dim3(782,4),blk,0,stream>>>(hin, Umat, uvec, denB, hpre, NN);
    ln_relu<<<dim3(12500),blk,0,stream>>>(hpre, lng, lnb, hout, NN);
  }
}

// Round 2
// 799.499 us; speedup vs baseline: 2.6963x; 2.6963x over previous
//
#include <hip/hip_runtime.h>

#define NN    50000
#define IN_CH 512
#define HID   256
#define PJ    1024
#define FN    50000.0f
#define KTP   50176          // padded node-dim for ht (= 49*1024), 784*64
#define NCH   49
#define CHK   1024
#define FWP   520            // FWT row stride (u16)
#define UTP   264            // Ut row stride (u16)

typedef __attribute__((ext_vector_type(4))) float f32x4;
typedef __attribute__((ext_vector_type(4))) int   i32x4;
typedef __attribute__((ext_vector_type(8))) unsigned short u16x8;

__device__ inline void mfma16(f32x4& c, i32x4 a, i32x4 b){
  asm("v_mfma_f32_16x16x32_bf16 %0, %1, %2, %0" : "+v"(c) : "v"(a), "v"(b));
}

__device__ inline unsigned short f2bf(float f){
  unsigned int u = __builtin_bit_cast(unsigned int, f);
  unsigned int r = (u + 0x7fffu + ((u >> 16) & 1u)) >> 16;
  return (unsigned short)r;
}

__device__ inline float wave_reduce(float v){
  #pragma unroll
  for(int o=32;o>0;o>>=1) v += __shfl_down(v,o,64);
  return v;
}

__device__ inline float block_reduce(float v, float* sh4){
  v = wave_reduce(v);
  int lane = threadIdx.x & 63, wv = threadIdx.x >> 6;
  if(lane==0) sh4[wv] = v;
  __syncthreads();
  float r = sh4[0]+sh4[1]+sh4[2]+sh4[3];
  __syncthreads();
  return r;
}

// ---------------- fc_w [512][256] fp32 -> FWT bf16 [256][FWP] (transposed)
__global__ void wconv(const float* __restrict__ w, unsigned short* __restrict__ wt){
  int idx = blockIdx.x*256 + threadIdx.x;
  if(idx >= IN_CH*HID) return;
  int k = idx >> 8, n = idx & 255;
  wt[(size_t)n*FWP + k] = f2bf(w[idx]);
}

// ---------------- FFN: buf = x(bf16-cvt in staging) @ fc_w + bias ----------
// BM=128 rows, BN=256 (all), BK=64, 8 waves (512 thr), wave=64x64
__global__ __launch_bounds__(512)
void ffn_gemm(const float* __restrict__ X, const unsigned short* __restrict__ FWT,
              const float* __restrict__ bias, float* __restrict__ out){
  __shared__ unsigned short as[128][72];
  __shared__ unsigned short bs[256][72];
  int t = threadIdx.x;
  int bm = blockIdx.x*128;
  int w = t>>6, lane = t&63;
  int wr = w>>2, wc = w&3;
  f32x4 acc[4][4];
  #pragma unroll
  for(int i=0;i<4;i++)
    #pragma unroll
    for(int j=0;j<4;j++) acc[i][j] = (f32x4){0.f,0.f,0.f,0.f};

  for(int k0=0;k0<IN_CH;k0+=64){
    { int r = t>>2, q = t&3;
      const float* src = X + (size_t)(bm+r)*IN_CH + k0 + q*16;
      bool ok = (bm+r) < NN;
      #pragma unroll
      for(int i=0;i<4;i++){
        float4 v = ok ? *(const float4*)(src + i*4) : make_float4(0.f,0.f,0.f,0.f);
        ushort4 u; u.x=f2bf(v.x); u.y=f2bf(v.y); u.z=f2bf(v.z); u.w=f2bf(v.w);
        *(ushort4*)&as[r][q*16 + i*4] = u;
      }
    }
    { int n = t>>1, q = t&1;
      const unsigned short* src = FWT + (size_t)n*FWP + k0 + q*32;
      #pragma unroll
      for(int i=0;i<4;i++)
        *(u16x8*)&bs[n][q*32 + i*8] = *(const u16x8*)(src + i*8);
    }
    __syncthreads();
    #pragma unroll
    for(int ks=0;ks<2;ks++){
      i32x4 af[4], bfv[4];
      #pragma unroll
      for(int i=0;i<4;i++) af[i]  = *(const i32x4*)&as[wr*64 + i*16 + (lane&15)][ks*32 + (lane>>4)*8];
      #pragma unroll
      for(int j=0;j<4;j++) bfv[j] = *(const i32x4*)&bs[wc*64 + j*16 + (lane&15)][ks*32 + (lane>>4)*8];
      #pragma unroll
      for(int i=0;i<4;i++)
        #pragma unroll
        for(int j=0;j<4;j++) mfma16(acc[i][j], af[i], bfv[j]);
    }
    __syncthreads();
  }
  int rb = bm + wr*64, cb = wc*64;
  #pragma unroll
  for(int i=0;i<4;i++)
    #pragma unroll
    for(int j=0;j<4;j++){
      int col = cb + j*16 + (lane&15);
      float b = bias[col];
      #pragma unroll
      for(int r=0;r<4;r++){
        int row = rb + i*16 + (lane>>4)*4 + r;
        if(row<NN) out[(size_t)row*HID + col] = acc[i][j][r] + b;
      }
    }
}

// ---------------- LN+ReLU, writes fp32 out (+optional bf16 copy) -----------
__global__ void ln_relu2(const float* __restrict__ in, const float* __restrict__ g,
                         const float* __restrict__ b, float* __restrict__ out,
                         unsigned short* __restrict__ outb, int M){
  int lane = threadIdx.x & 63, wv = threadIdx.x >> 6;
  int row = blockIdx.x*4 + wv;
  if(row>=M) return;
  const float* r = in + (size_t)row*HID;
  float v[4], sum=0.f, sq=0.f;
  #pragma unroll
  for(int j=0;j<4;j++){ v[j]=r[lane+j*64]; sum+=v[j]; sq+=v[j]*v[j]; }
  sum = wave_reduce(sum); sq = wave_reduce(sq);
  sum = __shfl(sum,0,64); sq = __shfl(sq,0,64);
  float mu = sum*(1.f/HID);
  float var = sq*(1.f/HID) - mu*mu;
  float rs = rsqrtf(var + 1e-5f);
  #pragma unroll
  for(int j=0;j<4;j++){ int c=lane+j*64;
    float y = fmaxf((v[j]-mu)*rs*g[c] + b[c], 0.f);
    out[(size_t)row*HID + c] = y;
    if(outb) outb[(size_t)row*HID + c] = f2bf(y);
  }
}

// ---------------- hb [NN][256] bf16 -> ht [256][KTP] bf16 (zero-padded) ----
__global__ __launch_bounds__(256)
void transpose_h(const unsigned short* __restrict__ hb, unsigned short* __restrict__ ht){
  __shared__ unsigned short ts[64][72];
  int r0 = blockIdx.x*64, c0 = blockIdx.y*64;
  int t = threadIdx.x;
  { int r = t&63, q = t>>6;
    #pragma unroll
    for(int i=0;i<2;i++){
      int c = q*16 + i*8;
      u16x8 v = {0,0,0,0,0,0,0,0};
      if(r0+r < NN) v = *(const u16x8*)(hb + (size_t)(r0+r)*HID + c0 + c);
      *(u16x8*)&ts[r][c] = v;
    }
  }
  __syncthreads();
  { int c = t>>2, q = t&3;
    unsigned short tmp[16];
    #pragma unroll
    for(int i=0;i<16;i++) tmp[i] = ts[q*16+i][c];
    unsigned short* dst = ht + (size_t)(c0+c)*KTP + r0 + q*16;
    *(u16x8*)(dst)   = *(u16x8*)&tmp[0];
    *(u16x8*)(dst+8) = *(u16x8*)&tmp[8];
  }
}

// ---------------- G = h^T h via MFMA on ht, split-K partials ---------------
__global__ __launch_bounds__(256)
void gram_mfma(const unsigned short* __restrict__ ht, float* __restrict__ gp){
  __shared__ unsigned short as[128][72], bs[128][72];
  int q = blockIdx.x, ch = blockIdx.y;
  int r0 = (q>>1)*128, c0 = (q&1)*128;
  int t = threadIdx.x, w=t>>6, lane=t&63;
  int wr=w>>1, wc=w&1;
  f32x4 acc[4][4];
  #pragma unroll
  for(int i=0;i<4;i++)
    #pragma unroll
    for(int j=0;j<4;j++) acc[i][j] = (f32x4){0.f,0.f,0.f,0.f};
  size_t kbase = (size_t)ch*CHK;
  for(int k0=0;k0<CHK;k0+=64){
    { int r = t>>1, h2 = t&1;
      const unsigned short* srcA = ht + (size_t)(r0+r)*KTP + kbase + k0 + h2*32;
      const unsigned short* srcB = ht + (size_t)(c0+r)*KTP + kbase + k0 + h2*32;
      #pragma unroll
      for(int i=0;i<4;i++) *(u16x8*)&as[r][h2*32+i*8] = *(const u16x8*)(srcA + i*8);
      #pragma unroll
      for(int i=0;i<4;i++) *(u16x8*)&bs[r][h2*32+i*8] = *(const u16x8*)(srcB + i*8);
    }
    __syncthreads();
    #pragma unroll
    for(int ks=0;ks<2;ks++){
      i32x4 af[4], bfv[4];
      #pragma unroll
      for(int i=0;i<4;i++) af[i]  = *(const i32x4*)&as[wr*64 + i*16 + (lane&15)][ks*32 + (lane>>4)*8];
      #pragma unroll
      for(int j=0;j<4;j++) bfv[j] = *(const i32x4*)&bs[wc*64 + j*16 + (lane&15)][ks*32 + (lane>>4)*8];
      #pragma unroll
      for(int i=0;i<4;i++)
        #pragma unroll
        for(int j=0;j<4;j++) mfma16(acc[i][j], af[i], bfv[j]);
    }
    __syncthreads();
  }
  float* dst = gp + ((size_t)q*NCH + ch)*16384;
  #pragma unroll
  for(int i=0;i<4;i++)
    #pragma unroll
    for(int j=0;j<4;j++)
      #pragma unroll
      for(int r=0;r<4;r++)
        dst[(wr*64+i*16+(lane>>4)*4+r)*128 + wc*64+j*16+(lane&15)] = acc[i][j][r];
}

__global__ void gram_reduce2(const float* __restrict__ gp, float* __restrict__ G){
  int q=blockIdx.x; int e = blockIdx.y*256 + threadIdx.x;
  const float* p = gp + (size_t)q*NCH*16384 + e;
  float s=0.f;
  for(int c=0;c<NCH;c++) s += p[(size_t)c*16384];
  int i = e>>7, j = e&127;
  int r0=(q>>1)*128, c0=(q&1)*128;
  G[(r0+i)*256 + c0+j] = s;
}

// ---------------- s = colsum(h) --------------------------------------------
__global__ void colsum_partial(const float* __restrict__ h, float* __restrict__ cp, int M){
  int col = threadIdx.x, ch = blockIdx.x;
  int n0 = ch*391; int n1 = n0+391; if(n1>M) n1=M;
  float s=0.f;
  for(int n=n0;n<n1;n++) s += h[(size_t)n*HID + col];
  cp[ch*256+col]=s;
}
__global__ void colsum_reduce(const float* __restrict__ cp, float* __restrict__ s){
  int col=threadIdx.x; float v=0.f;
  for(int c=0;c<128;c++) v += cp[c*256+col];
  s[col]=v;
}

// ---------------- gw_z = G @ W_z (z=0,1,2) fp32 ----------------------------
__global__ void gw_gemm3(const float* __restrict__ G, const float* __restrict__ Wq,
                         const float* __restrict__ Wk, const float* __restrict__ Wv,
                         float* __restrict__ gw){
  const float* B = blockIdx.z==0?Wq:(blockIdx.z==1?Wk:Wv);
  float* C = gw + (size_t)blockIdx.z*262144;
  __shared__ float As[64][33];
  __shared__ float Bs[32][64];
  int bm = blockIdx.x*64, bn = blockIdx.y*64;
  int t = threadIdx.x;
  int tn = t & 15, tm = t >> 4;
  float acc[4][4] = {};
  for(int k0=0;k0<HID;k0+=32){
    { int kk=t&31, rr=t>>5;
      #pragma unroll
      for(int p=0;p<8;p++){ int r=rr+p*8;
        As[r][kk] = G[(size_t)(bm+r)*HID + k0+kk]; } }
    { int nn=t&63, kr=t>>6;
      #pragma unroll
      for(int p=0;p<8;p++){ int k=kr+p*4;
        Bs[k][nn] = B[(size_t)(k0+k)*PJ + bn+nn]; } }
    __syncthreads();
    for(int k=0;k<32;k++){
      float a[4], b[4];
      #pragma unroll
      for(int i=0;i<4;i++) a[i]=As[tm*4+i][k];
      #pragma unroll
      for(int j=0;j<4;j++) b[j]=Bs[k][tn*4+j];
      #pragma unroll
      for(int i=0;i<4;i++)
        #pragma unroll
        for(int j=0;j<4;j++) acc[i][j] += a[i]*b[j];
    }
    __syncthreads();
  }
  #pragma unroll
  for(int i=0;i<4;i++)
    #pragma unroll
    for(int j=0;j<4;j++)
      C[(size_t)(bm+tm*4+i)*PJ + bn+tn*4+j] = acc[i][j];
}

// ---------------- a{q,k,v} = W^T s -----------------------------------------
__global__ void wt_s(const float* __restrict__ Wq, const float* __restrict__ Wk,
                     const float* __restrict__ Wv, const float* __restrict__ s,
                     float* __restrict__ avec){
  const float* Wsel = (blockIdx.x==0)?Wq:(blockIdx.x==1)?Wk:Wv;
  int col = blockIdx.y*256 + threadIdx.x;
  __shared__ float ss[256];
  ss[threadIdx.x]=s[threadIdx.x];
  __syncthreads();
  float acc=0.f;
  for(int i=0;i<256;i++) acc += Wsel[(size_t)i*PJ + col]*ss[i];
  avec[blockIdx.x*1024 + col]=acc;
}

// ---------------- trace terms ----------------------------------------------
__global__ void trace_partial(const float* __restrict__ Wq, const float* __restrict__ Wk,
                              const float* __restrict__ gw, float* __restrict__ trp){
  int which = blockIdx.x;
  const float* Wsel = which ? Wk : Wq;
  const float* GW = gw + (size_t)which*262144;
  int t=threadIdx.x;
  int base = blockIdx.y*4096 + t;
  float s=0.f;
  #pragma unroll
  for(int i=0;i<16;i++){ int idx=base+i*256; s += Wsel[idx]*GW[idx]; }
  __shared__ float sh4[4];
  float r = block_reduce(s, sh4);
  if(t==0) trp[which*64 + blockIdx.y] = r;
}

__global__ void finalize_scalars(const float* __restrict__ trp, const float* __restrict__ bq,
                                 const float* __restrict__ bk, const float* __restrict__ avec,
                                 float* __restrict__ ksum, float* __restrict__ scal){
  __shared__ float sh4[4];
  int t=threadIdx.x;
  float pq = (t<64)? trp[t]    : 0.f;
  float pk = (t<64)? trp[64+t] : 0.f;
  float bqaq=0.f,bkak=0.f,bq2=0.f,bk2=0.f;
  #pragma unroll
  for(int p=0;p<4;p++){ int jn=t+p*256;
    float qv=bq[jn], kv=bk[jn];
    bqaq += qv*avec[jn]; bkak += kv*avec[1024+jn];
    bq2 += qv*qv; bk2 += kv*kv; }
  float tq = block_reduce(pq, sh4);
  float tk = block_reduce(pk, sh4);
  float s1 = block_reduce(bqaq, sh4);
  float s2 = block_reduce(bkak, sh4);
  float s3 = block_reduce(bq2, sh4);
  float s4 = block_reduce(bk2, sh4);
  if(t==0){
    float q2 = tq + 2.f*s1 + FN*s3;
    float k2 = tk + 2.f*s2 + FN*s4;
    scal[0] = rsqrtf(q2)*rsqrtf(k2);
  }
  #pragma unroll
  for(int p=0;p<4;p++){ int jn=t+p*256; ksum[jn] = avec[1024+jn] + FN*bk[jn]; }
}

// ---------------- kvs ------------------------------------------------------
__global__ void kvs_k(const float* __restrict__ Wk, const float* __restrict__ GWv,
                      const float* __restrict__ avec, const float* __restrict__ bk,
                      const float* __restrict__ bv, float* __restrict__ kvs){
  int hh=blockIdx.x, tile=blockIdx.y;
  int m0=(tile>>2)*64, d0=(tile&3)*64;
  __shared__ float As[32][64], Bs[32][64];
  int t=threadIdx.x, tn=t&15, tm=t>>4;
  float acc[4][4]={};
  for(int k0=0;k0<256;k0+=32){
    int kr=t>>6, cc=t&63;
    #pragma unroll
    for(int p=0;p<8;p++){
      int k=kr+p*4;
      As[k][cc] = Wk [(size_t)(k0+k)*PJ + hh*256 + m0+cc];
      Bs[k][cc] = GWv[(size_t)(k0+k)*PJ + hh*256 + d0+cc];
    }
    __syncthreads();
    for(int k=0;k<32;k++){
      float a[4], b[4];
      #pragma unroll
      for(int i=0;i<4;i++) a[i]=As[k][tm*4+i];
      #pragma unroll
      for(int j=0;j<4;j++) b[j]=Bs[k][tn*4+j];
      #pragma unroll
      for(int i=0;i<4;i++)
        #pragma unroll
        for(int j=0;j<4;j++) acc[i][j] += a[i]*b[j];
    }
    __syncthreads();
  }
  const float* ak = avec+1024; const float* av = avec+2048;
  #pragma unroll
  for(int i=0;i<4;i++)
    #pragma unroll
    for(int j=0;j<4;j++){
      int m=m0+tm*4+i, d=d0+tn*4+j;
      float akm=ak[hh*256+m], bkm=bk[hh*256+m];
      float avd=av[hh*256+d], bvd=bv[hh*256+d];
      kvs[(size_t)hh*65536 + m*256 + d] = acc[i][j] + akm*bvd + bkm*avd + FN*bkm*bvd;
    }
}

// -------- U = scale*Wq@kvs + N*Wv, written transposed bf16 -> Ut[1024][UTP]
__global__ void u_gemm(const float* __restrict__ Wq, const float* __restrict__ kvs,
                       const float* __restrict__ Wv, const float* __restrict__ scal,
                       unsigned short* __restrict__ Ut){
  int hh=blockIdx.x, tile=blockIdx.y;
  int i0=(tile>>2)*64, d0=(tile&3)*64;
  __shared__ float As[64][33]; __shared__ float Bs[32][64];
  __shared__ unsigned short ts[64][72];
  int t=threadIdx.x, tn=t&15, tm=t>>4;
  float acc[4][4]={};
  for(int k0=0;k0<256;k0+=32){
    { int kk=t&31, rr=t>>5;
      #pragma unroll
      for(int p=0;p<8;p++){ int r=rr+p*8;
        As[r][kk] = Wq[(size_t)(i0+r)*PJ + hh*256 + k0+kk]; } }
    { int kr=t>>6, cc=t&63;
      #pragma unroll
      for(int p=0;p<8;p++){ int k=kr+p*4;
        Bs[k][cc] = kvs[(size_t)hh*65536 + (k0+k)*256 + d0+cc]; } }
    __syncthreads();
    for(int k=0;k<32;k++){
      float a[4], b[4];
      #pragma unroll
      for(int i=0;i<4;i++) a[i]=As[tm*4+i][k];
      #pragma unroll
      for(int j=0;j<4;j++) b[j]=Bs[k][tn*4+j];
      #pragma unroll
      for(int i=0;i<4;i++)
        #pragma unroll
        for(int j=0;j<4;j++) acc[i][j] += a[i]*b[j];
    }
    __syncthreads();
  }
  float sc = scal[0];
  #pragma unroll
  for(int i=0;i<4;i++)
    #pragma unroll
    for(int j=0;j<4;j++){
      int ii=i0+tm*4+i, d=d0+tn*4+j;
      float val = sc*acc[i][j] + FN*Wv[(size_t)ii*PJ + hh*256 + d];
      ts[tn*4+j][tm*4+i] = f2bf(val);
    }
  __syncthreads();
  { int ld = t>>2, q = t&3;
    unsigned short tmp[16];
    #pragma unroll
    for(int i=0;i<16;i++) tmp[i]=ts[ld][q*16+i];
    unsigned short* dst = Ut + (size_t)(hh*256+d0+ld)*UTP + i0 + q*16;
    *(u16x8*)(dst)   = *(u16x8*)&tmp[0];
    *(u16x8*)(dst+8) = *(u16x8*)&tmp[8];
  }
}

// ---------------- per-head vectors -----------------------------------------
__global__ void head_vecs(const float* __restrict__ Wq, const float* __restrict__ bq,
                          const float* __restrict__ bv, const float* __restrict__ kvs,
                          const float* __restrict__ ksum, const float* __restrict__ scal,
                          float* __restrict__ uvec, float* __restrict__ wvec,
                          float* __restrict__ cvec){
  int hh=blockIdx.x, t=threadIdx.x;
  float scale=scal[0];
  __shared__ float bqs[256], kss[256];
  __shared__ float sh4[4];
  bqs[t]=bq[hh*256+t]; kss[t]=ksum[hh*256+t];
  __syncthreads();
  float su=0.f;
  for(int m=0;m<256;m++) su += bqs[m]*kvs[(size_t)hh*65536 + m*256 + t];
  uvec[hh*256+t] = scale*su + FN*bv[hh*256+t];
  float sw=0.f;
  for(int m=0;m<256;m++) sw += Wq[(size_t)t*PJ + hh*256 + m]*kss[m];
  wvec[hh*256+t] = scale*sw;
  float pc = bqs[t]*kss[t];
  float total = block_reduce(pc, sh4);
  if(t==0) cvec[hh] = scale*total + FN;
}

// ---------------- denom (stores reciprocal) --------------------------------
__global__ void denom_k(const float* __restrict__ h, const float* __restrict__ wvec,
                        const float* __restrict__ cvec, float* __restrict__ denom, int M){
  __shared__ float wvl[1024];
  for(int i=threadIdx.x;i<1024;i+=256) wvl[i]=wvec[i];
  __syncthreads();
  int lane=threadIdx.x&63, wv=threadIdx.x>>6;
  int row=blockIdx.x*4+wv;
  if(row>=M) return;
  float p[4]={0.f,0.f,0.f,0.f};
  #pragma unroll
  for(int j=0;j<4;j++){
    float hv = h[(size_t)row*HID + lane + j*64];
    #pragma unroll
    for(int hh=0;hh<4;hh++) p[hh] += hv*wvl[hh*256 + lane + j*64];
  }
  #pragma unroll
  for(int hh=0;hh<4;hh++) p[hh]=wave_reduce(p[hh]);
  if(lane==0){
    #pragma unroll
    for(int hh=0;hh<4;hh++) denom[(size_t)row*4+hh] = 1.0f/(p[hh]+cvec[hh]);
  }
}

// ---------------- attn MFMA: out = ((h@U+u)/denom mean + h)/2 --------------
// BM=64 (4 waves x 16 rows), col strip 64 (x4 heads internal), BK=64
__global__ __launch_bounds__(256)
void attn_mfma(const unsigned short* __restrict__ hb, const unsigned short* __restrict__ Ut,
               const float* __restrict__ uvec, const float* __restrict__ rden,
               const float* __restrict__ hin, float* __restrict__ outp){
  __shared__ unsigned short as[64][72];
  __shared__ unsigned short bs[256][72];
  int bm = blockIdx.x*64;
  int c0 = blockIdx.y*64;
  int t = threadIdx.x, w = t>>6, lane = t&63;
  f32x4 acc[4][4];   // [head][jc]
  #pragma unroll
  for(int i=0;i<4;i++)
    #pragma unroll
    for(int j=0;j<4;j++) acc[i][j] = (f32x4){0.f,0.f,0.f,0.f};

  for(int k0=0;k0<HID;k0+=64){
    { int r = t>>2, q = t&3;
      const unsigned short* src = hb + (size_t)(bm+r)*HID + k0 + q*16;
      u16x8 v0={0,0,0,0,0,0,0,0}, v1={0,0,0,0,0,0,0,0};
      if(bm+r<NN){ v0=*(const u16x8*)src; v1=*(const u16x8*)(src+8); }
      *(u16x8*)&as[r][q*16] = v0; *(u16x8*)&as[r][q*16+8] = v1;
    }
    { int rr = t;
      int gn = (rr>>6)*256 + c0 + (rr&63);
      const unsigned short* src = Ut + (size_t)gn*UTP + k0;
      #pragma unroll
      for(int i=0;i<8;i++) *(u16x8*)&bs[rr][i*8] = *(const u16x8*)(src+i*8);
    }
    __syncthreads();
    #pragma unroll
    for(int ks=0;ks<2;ks++){
      i32x4 af = *(const i32x4*)&as[w*16 + (lane&15)][ks*32 + (lane>>4)*8];
      #pragma unroll
      for(int h=0;h<4;h++)
        #pragma unroll
        for(int j=0;j<4;j++){
          i32x4 bfv = *(const i32x4*)&bs[h*64 + j*16 + (lane&15)][ks*32 + (lane>>4)*8];
          mfma16(acc[h][j], af, bfv);
        }
    }
    __syncthreads();
  }
  int rowb = bm + w*16 + (lane>>4)*4;
  float rd[4][4];   // [r][h]
  #pragma unroll
  for(int r=0;r<4;r++){
    int gr = rowb + r;
    #pragma unroll
    for(int h=0;h<4;h++) rd[r][h] = (gr<NN) ? rden[(size_t)gr*4+h] : 0.f;
  }
  #pragma unroll
  for(int j=0;j<4;j++){
    int gc = c0 + j*16 + (lane&15);
    float uv[4];
    #pragma unroll
    for(int h=0;h<4;h++) uv[h] = uvec[h*256 + gc];
    #pragma unroll
    for(int r=0;r<4;r++){
      int gr = rowb + r;
      if(gr>=NN) continue;
      float v = 0.f;
      #pragma unroll
      for(int h=0;h<4;h++) v += (acc[h][j][r] + uv[h]) * rd[r][h];
      v *= 0.25f;
      outp[(size_t)gr*HID + gc] = (v + hin[(size_t)gr*HID + gc]) * 0.5f;
    }
  }
}

extern "C" void kernel_launch(void* const* d_in, const int* in_sizes, int n_in,
                              void* d_out, int out_size, void* d_ws, size_t ws_size,
                              hipStream_t stream){
  const float* x    = (const float*)d_in[0];
  const float* fc_w = (const float*)d_in[1];
  const float* fc_b = (const float*)d_in[2];
  const float* ln0g = (const float*)d_in[3];
  const float* ln0b = (const float*)d_in[4];
  float* out = (float*)d_out;

  float* W = (float*)d_ws;
  size_t o=0;
  float* buf0 = W+o; o+=(size_t)NN*HID;
  float* buf1 = W+o; o+=(size_t)NN*HID;
  unsigned short* hb  = (unsigned short*)(W+o); o+=(size_t)NN*HID/2;
  unsigned short* ht  = (unsigned short*)(W+o); o+=(size_t)HID*KTP/2;
  unsigned short* FWT = (unsigned short*)(W+o); o+=(size_t)HID*FWP/2 + 8;
  unsigned short* Ut  = (unsigned short*)(W+o); o+=(size_t)PJ*UTP/2 + 8;
  float* gramp= W+o; o+=(size_t)4*NCH*16384;
  float* G    = W+o; o+=65536;
  float* gw   = W+o; o+=3*262144;
  float* colp = W+o; o+=128*256;
  float* svec = W+o; o+=256;
  float* avec = W+o; o+=3072;
  float* trp  = W+o; o+=128;
  float* scal = W+o; o+=16;
  float* ksum = W+o; o+=1024;
  float* kvs  = W+o; o+=262144;
  float* uvec = W+o; o+=1024;
  float* wvec = W+o; o+=1024;
  float* cvec = W+o; o+=8;
  float* denB = W+o; o+=(size_t)NN*4;
  (void)ws_size; (void)in_sizes; (void)n_in; (void)out_size;

  dim3 blk(256);
  wconv<<<dim3(512),blk,0,stream>>>(fc_w, FWT);
  ffn_gemm<<<dim3(391),dim3(512),0,stream>>>(x, FWT, fc_b, buf0);
  ln_relu2<<<dim3(12500),blk,0,stream>>>(buf0, ln0g, ln0b, buf0, hb, NN);

  for(int L=0; L<2; L++){
    const float* wq = (const float*)d_in[5+L*8+0];
    const float* bq = (const float*)d_in[5+L*8+1];
    const float* wk = (const float*)d_in[5+L*8+2];
    const float* bk = (const float*)d_in[5+L*8+3];
    const float* wv = (const float*)d_in[5+L*8+4];
    const float* bv = (const float*)d_in[5+L*8+5];
    const float* lng= (const float*)d_in[5+L*8+6];
    const float* lnb= (const float*)d_in[5+L*8+7];
    const float* hin = buf0;
    float* hpre = buf1;
    float* hout = L ? out : buf0;
    unsigned short* hbn = L ? (unsigned short*)nullptr : hb;

    transpose_h<<<dim3(784,4),blk,0,stream>>>(hb, ht);
    gram_mfma<<<dim3(4,NCH),blk,0,stream>>>(ht, gramp);
    gram_reduce2<<<dim3(4,64),blk,0,stream>>>(gramp, G);
    colsum_partial<<<dim3(128),blk,0,stream>>>(hin, colp, NN);
    colsum_reduce<<<dim3(1),blk,0,stream>>>(colp, svec);
    gw_gemm3<<<dim3(4,16,3),blk,0,stream>>>(G, wq, wk, wv, gw);
    wt_s<<<dim3(3,4),blk,0,stream>>>(wq,wk,wv,svec,avec);
    trace_partial<<<dim3(2,64),blk,0,stream>>>(wq,wk,gw,trp);
    finalize_scalars<<<dim3(1),blk,0,stream>>>(trp,bq,bk,avec,ksum,scal);
    kvs_k<<<dim3(4,16),blk,0,stream>>>(wk, gw+2*262144, avec, bk, bv, kvs);
    u_gemm<<<dim3(4,16),blk,0,stream>>>(wq, kvs, wv, scal, Ut);
    head_vecs<<<dim3(4),blk,0,stream>>>(wq,bq,bv,kvs,ksum,scal,uvec,wvec,cvec);
    denom_k<<<dim3(12500),blk,0,stream>>>(hin, wvec, cvec, denB, NN);
    attn_mfma<<<dim3(782,4),blk,0,stream>>>(hb, Ut, uvec, denB, hin, hpre);
    ln_relu2<<<dim3(12500),blk,0,stream>>>(hpre, lng, lnb, hout, hbn, NN);
  }
}

// Round 3
// 610.422 us; speedup vs baseline: 3.5314x; 1.3097x over previous
//
#include <hip/hip_runtime.h>

#define NN    50000
#define IN_CH 512
#define HID   256
#define PJ    1024
#define FN    50000.0f
#define KTP   50176          // padded node-dim for ht (784*64)
#define NCH   98
#define CHK   512
#define FWP   520            // FWT row stride (u16)
#define UTP   264            // Ut row stride (u16)

typedef __attribute__((ext_vector_type(4)))  float f32x4;
typedef __attribute__((ext_vector_type(16))) float f32x16;
typedef __attribute__((ext_vector_type(4)))  int   i32x4;
typedef __attribute__((ext_vector_type(8)))  unsigned short u16x8;

__device__ inline void mfma16(f32x4& c, i32x4 a, i32x4 b){
  asm("v_mfma_f32_16x16x32_bf16 %0, %1, %2, %0" : "+v"(c) : "v"(a), "v"(b));
}
__device__ inline void mfma32(f32x16& c, i32x4 a, i32x4 b){
  asm("v_mfma_f32_32x32x16_bf16 %0, %1, %2, %0" : "+v"(c) : "v"(a), "v"(b));
}

__device__ inline unsigned short f2bf(float f){
  unsigned int u = __builtin_bit_cast(unsigned int, f);
  unsigned int r = (u + 0x7fffu + ((u >> 16) & 1u)) >> 16;
  return (unsigned short)r;
}
__device__ inline float bf2f(unsigned short u){
  unsigned int x = ((unsigned int)u) << 16;
  return __builtin_bit_cast(float, x);
}

__device__ inline float wave_reduce(float v){
  #pragma unroll
  for(int o=32;o>0;o>>=1) v += __shfl_down(v,o,64);
  return v;
}
__device__ inline float block_reduce(float v, float* sh4){
  v = wave_reduce(v);
  int lane = threadIdx.x & 63, wv = threadIdx.x >> 6;
  if(lane==0) sh4[wv] = v;
  __syncthreads();
  float r = sh4[0]+sh4[1]+sh4[2]+sh4[3];
  __syncthreads();
  return r;
}

// ---------------- fc_w [512][256] fp32 -> FWT bf16 [256][FWP] (transposed)
__global__ void wconv(const float* __restrict__ w, unsigned short* __restrict__ wt){
  int idx = blockIdx.x*256 + threadIdx.x;
  if(idx >= IN_CH*HID) return;
  int k = idx >> 8, n = idx & 255;
  wt[(size_t)n*FWP + k] = f2bf(w[idx]);
}

// ---------------- FFN + fused LN + ReLU -> hb bf16 -------------------------
// BM=128 rows, BN=256 (full row), BK=64, 8 waves; wave (wr,wc) = 64x64 tile
__global__ __launch_bounds__(512)
void ffn_gemm(const float* __restrict__ X, const unsigned short* __restrict__ FWT,
              const float* __restrict__ bias, const float* __restrict__ g,
              const float* __restrict__ b2, unsigned short* __restrict__ hbo){
  __shared__ __align__(16) unsigned char smem[55296];
  unsigned short (*as)[72] = (unsigned short(*)[72])smem;            // 128x72
  unsigned short (*bs)[72] = (unsigned short(*)[72])(smem + 18432);  // 256x72
  int t = threadIdx.x;
  int bm = blockIdx.x*128;
  int w = t>>6, lane = t&63;
  int wr = w>>2, wc = w&3;
  f32x4 acc[4][4];
  #pragma unroll
  for(int i=0;i<4;i++)
    #pragma unroll
    for(int j=0;j<4;j++) acc[i][j] = (f32x4){0.f,0.f,0.f,0.f};

  for(int k0=0;k0<IN_CH;k0+=64){
    { int r = t>>2, q = t&3;
      const float* src = X + (size_t)(bm+r)*IN_CH + k0 + q*16;
      bool ok = (bm+r) < NN;
      #pragma unroll
      for(int i=0;i<4;i++){
        float4 v = ok ? *(const float4*)(src + i*4) : make_float4(0.f,0.f,0.f,0.f);
        ushort4 u; u.x=f2bf(v.x); u.y=f2bf(v.y); u.z=f2bf(v.z); u.w=f2bf(v.w);
        *(ushort4*)&as[r][q*16 + i*4] = u;
      }
    }
    { int n = t>>1, q = t&1;
      const unsigned short* src = FWT + (size_t)n*FWP + k0 + q*32;
      #pragma unroll
      for(int i=0;i<4;i++)
        *(u16x8*)&bs[n][q*32 + i*8] = *(const u16x8*)(src + i*8);
    }
    __syncthreads();
    #pragma unroll
    for(int ks=0;ks<2;ks++){
      i32x4 af[4], bfv[4];
      #pragma unroll
      for(int i=0;i<4;i++) af[i]  = *(const i32x4*)&as[wr*64 + i*16 + (lane&15)][ks*32 + (lane>>4)*8];
      #pragma unroll
      for(int j=0;j<4;j++) bfv[j] = *(const i32x4*)&bs[wc*64 + j*16 + (lane&15)][ks*32 + (lane>>4)*8];
      #pragma unroll
      for(int i=0;i<4;i++)
        #pragma unroll
        for(int j=0;j<4;j++) mfma16(acc[i][j], af[i], bfv[j]);
    }
    __syncthreads();
  }
  int cb = wc*64;
  // add bias
  #pragma unroll
  for(int j=0;j<4;j++){
    float bb = bias[cb + j*16 + (lane&15)];
    #pragma unroll
    for(int i=0;i<4;i++)
      #pragma unroll
      for(int r=0;r<4;r++) acc[i][j][r] += bb;
  }
  // LN stats: per-row partials across this wave's 64 cols
  float (*lnp)[4][2] = (float(*)[4][2])smem;         // 128 x 4 x 2
  float (*lnstat)[2] = (float(*)[2])(smem + 4096);   // 128 x 2
  #pragma unroll
  for(int i=0;i<4;i++)
    #pragma unroll
    for(int r=0;r<4;r++){
      float s=0.f, q=0.f;
      #pragma unroll
      for(int j=0;j<4;j++){ float a=acc[i][j][r]; s+=a; q+=a*a; }
      #pragma unroll
      for(int m=1;m<16;m<<=1){ s += __shfl_xor(s,m,64); q += __shfl_xor(q,m,64); }
      if((lane&15)==0){
        int row = wr*64 + i*16 + (lane>>4)*4 + r;
        lnp[row][wc][0]=s; lnp[row][wc][1]=q;
      }
    }
  __syncthreads();
  if(t<128){
    float s=0.f,q=0.f;
    #pragma unroll
    for(int c=0;c<4;c++){ s+=lnp[t][c][0]; q+=lnp[t][c][1]; }
    float mu = s*(1.f/HID);
    float var = q*(1.f/HID) - mu*mu;
    lnstat[t][0]=mu; lnstat[t][1]=rsqrtf(var+1e-5f);
  }
  __syncthreads();
  #pragma unroll
  for(int j=0;j<4;j++){
    int col = cb + j*16 + (lane&15);
    float gg = g[col], bb = b2[col];
    #pragma unroll
    for(int i=0;i<4;i++)
      #pragma unroll
      for(int r=0;r<4;r++){
        int row = wr*64 + i*16 + (lane>>4)*4 + r;
        int grow = bm + row;
        if(grow<NN){
          float y = fmaxf((acc[i][j][r]-lnstat[row][0])*lnstat[row][1]*gg + bb, 0.f);
          hbo[(size_t)grow*HID + col] = f2bf(y);
        }
      }
  }
}

// ---------------- LN+ReLU (post-attn): fp32 in -> bf16 and/or fp32 out -----
__global__ void ln_relu2(const float* __restrict__ in, const float* __restrict__ g,
                         const float* __restrict__ b, unsigned short* __restrict__ outb,
                         float* __restrict__ outf, int M){
  int lane = threadIdx.x & 63, wv = threadIdx.x >> 6;
  int row = blockIdx.x*4 + wv;
  if(row>=M) return;
  const float* r = in + (size_t)row*HID;
  float v[4], sum=0.f, sq=0.f;
  #pragma unroll
  for(int j=0;j<4;j++){ v[j]=r[lane+j*64]; sum+=v[j]; sq+=v[j]*v[j]; }
  sum = wave_reduce(sum); sq = wave_reduce(sq);
  sum = __shfl(sum,0,64); sq = __shfl(sq,0,64);
  float mu = sum*(1.f/HID);
  float var = sq*(1.f/HID) - mu*mu;
  float rs = rsqrtf(var + 1e-5f);
  #pragma unroll
  for(int j=0;j<4;j++){ int c=lane+j*64;
    float y = fmaxf((v[j]-mu)*rs*g[c] + b[c], 0.f);
    if(outb) outb[(size_t)row*HID + c] = f2bf(y);
    if(outf) outf[(size_t)row*HID + c] = y;
  }
}

// ---------------- hb [NN][256] bf16 -> ht [256][KTP] bf16 (zero-padded) ----
__global__ __launch_bounds__(256)
void transpose_h(const unsigned short* __restrict__ hb, unsigned short* __restrict__ ht){
  __shared__ unsigned short ts[64][72];
  int r0 = blockIdx.x*64, c0 = blockIdx.y*64;
  int t = threadIdx.x;
  { int r = t&63, q = t>>6;
    #pragma unroll
    for(int i=0;i<2;i++){
      int c = q*16 + i*8;
      u16x8 v = {0,0,0,0,0,0,0,0};
      if(r0+r < NN) v = *(const u16x8*)(hb + (size_t)(r0+r)*HID + c0 + c);
      *(u16x8*)&ts[r][c] = v;
    }
  }
  __syncthreads();
  { int c = t>>2, q = t&3;
    unsigned short tmp[16];
    #pragma unroll
    for(int i=0;i<16;i++) tmp[i] = ts[q*16+i][c];
    unsigned short* dst = ht + (size_t)(c0+c)*KTP + r0 + q*16;
    *(u16x8*)(dst)   = *(u16x8*)&tmp[0];
    *(u16x8*)(dst+8) = *(u16x8*)&tmp[8];
  }
}

// ---------------- G = h^T h via MFMA on ht, split-K partials ---------------
__global__ __launch_bounds__(256)
void gram_mfma(const unsigned short* __restrict__ ht, float* __restrict__ gp){
  __shared__ unsigned short as[128][72], bs[128][72];
  int q = blockIdx.x, ch = blockIdx.y;
  int r0 = (q>>1)*128, c0 = (q&1)*128;
  int t = threadIdx.x, w=t>>6, lane=t&63;
  int wr=w>>1, wc=w&1;
  f32x4 acc[4][4];
  #pragma unroll
  for(int i=0;i<4;i++)
    #pragma unroll
    for(int j=0;j<4;j++) acc[i][j] = (f32x4){0.f,0.f,0.f,0.f};
  size_t kbase = (size_t)ch*CHK;
  for(int k0=0;k0<CHK;k0+=64){
    { int r = t>>1, h2 = t&1;
      const unsigned short* srcA = ht + (size_t)(r0+r)*KTP + kbase + k0 + h2*32;
      const unsigned short* srcB = ht + (size_t)(c0+r)*KTP + kbase + k0 + h2*32;
      #pragma unroll
      for(int i=0;i<4;i++) *(u16x8*)&as[r][h2*32+i*8] = *(const u16x8*)(srcA + i*8);
      #pragma unroll
      for(int i=0;i<4;i++) *(u16x8*)&bs[r][h2*32+i*8] = *(const u16x8*)(srcB + i*8);
    }
    __syncthreads();
    #pragma unroll
    for(int ks=0;ks<2;ks++){
      i32x4 af[4], bfv[4];
      #pragma unroll
      for(int i=0;i<4;i++) af[i]  = *(const i32x4*)&as[wr*64 + i*16 + (lane&15)][ks*32 + (lane>>4)*8];
      #pragma unroll
      for(int j=0;j<4;j++) bfv[j] = *(const i32x4*)&bs[wc*64 + j*16 + (lane&15)][ks*32 + (lane>>4)*8];
      #pragma unroll
      for(int i=0;i<4;i++)
        #pragma unroll
        for(int j=0;j<4;j++) mfma16(acc[i][j], af[i], bfv[j]);
    }
    __syncthreads();
  }
  float* dst = gp + ((size_t)q*NCH + ch)*16384;
  #pragma unroll
  for(int i=0;i<4;i++)
    #pragma unroll
    for(int j=0;j<4;j++)
      #pragma unroll
      for(int r=0;r<4;r++)
        dst[(wr*64+i*16+(lane>>4)*4+r)*128 + wc*64+j*16+(lane&15)] = acc[i][j][r];
}

__global__ void gram_reduce2(const float* __restrict__ gp, float* __restrict__ G){
  int q=blockIdx.x; int e = blockIdx.y*256 + threadIdx.x;
  const float* p = gp + (size_t)q*NCH*16384 + e;
  float s=0.f;
  for(int c=0;c<NCH;c++) s += p[(size_t)c*16384];
  int i = e>>7, j = e&127;
  int r0=(q>>1)*128, c0=(q&1)*128;
  G[(r0+i)*256 + c0+j] = s;
}

// ---------------- svec[col] = sum_n h[n][col]  (row-sums of ht) ------------
__global__ void rowsum_ht(const unsigned short* __restrict__ ht, float* __restrict__ svec){
  int row = blockIdx.x;
  const unsigned short* p = ht + (size_t)row*KTP;
  float s = 0.f;
  for(int i = threadIdx.x*8; i < KTP; i += 2048){
    u16x8 v = *(const u16x8*)(p + i);
    #pragma unroll
    for(int e=0;e<8;e++) s += bf2f(v[e]);
  }
  __shared__ float sh4[4];
  float tot = block_reduce(s, sh4);
  if(threadIdx.x==0) svec[row] = tot;
}

// ---------------- gw_z = G @ W_z (z=0,1,2) fp32 ----------------------------
__global__ void gw_gemm3(const float* __restrict__ G, const float* __restrict__ Wq,
                         const float* __restrict__ Wk, const float* __restrict__ Wv,
                         float* __restrict__ gw){
  const float* B = blockIdx.z==0?Wq:(blockIdx.z==1?Wk:Wv);
  float* C = gw + (size_t)blockIdx.z*262144;
  __shared__ float As[64][33];
  __shared__ float Bs[32][64];
  int bm = blockIdx.x*64, bn = blockIdx.y*64;
  int t = threadIdx.x;
  int tn = t & 15, tm = t >> 4;
  float acc[4][4] = {};
  for(int k0=0;k0<HID;k0+=32){
    { int kk=t&31, rr=t>>5;
      #pragma unroll
      for(int p=0;p<8;p++){ int r=rr+p*8;
        As[r][kk] = G[(size_t)(bm+r)*HID + k0+kk]; } }
    { int nn=t&63, kr=t>>6;
      #pragma unroll
      for(int p=0;p<8;p++){ int k=kr+p*4;
        Bs[k][nn] = B[(size_t)(k0+k)*PJ + bn+nn]; } }
    __syncthreads();
    for(int k=0;k<32;k++){
      float a[4], b[4];
      #pragma unroll
      for(int i=0;i<4;i++) a[i]=As[tm*4+i][k];
      #pragma unroll
      for(int j=0;j<4;j++) b[j]=Bs[k][tn*4+j];
      #pragma unroll
      for(int i=0;i<4;i++)
        #pragma unroll
        for(int j=0;j<4;j++) acc[i][j] += a[i]*b[j];
    }
    __syncthreads();
  }
  #pragma unroll
  for(int i=0;i<4;i++)
    #pragma unroll
    for(int j=0;j<4;j++)
      C[(size_t)(bm+tm*4+i)*PJ + bn+tn*4+j] = acc[i][j];
}

// ---------------- a{q,k,v} = W^T s -----------------------------------------
__global__ void wt_s(const float* __restrict__ Wq, const float* __restrict__ Wk,
                     const float* __restrict__ Wv, const float* __restrict__ s,
                     float* __restrict__ avec){
  const float* Wsel = (blockIdx.x==0)?Wq:(blockIdx.x==1)?Wk:Wv;
  int col = blockIdx.y*256 + threadIdx.x;
  __shared__ float ss[256];
  ss[threadIdx.x]=s[threadIdx.x];
  __syncthreads();
  float acc=0.f;
  for(int i=0;i<256;i++) acc += Wsel[(size_t)i*PJ + col]*ss[i];
  avec[blockIdx.x*1024 + col]=acc;
}

// ---------------- trace terms ----------------------------------------------
__global__ void trace_partial(const float* __restrict__ Wq, const float* __restrict__ Wk,
                              const float* __restrict__ gw, float* __restrict__ trp){
  int which = blockIdx.x;
  const float* Wsel = which ? Wk : Wq;
  const float* GW = gw + (size_t)which*262144;
  int t=threadIdx.x;
  int base = blockIdx.y*4096 + t;
  float s=0.f;
  #pragma unroll
  for(int i=0;i<16;i++){ int idx=base+i*256; s += Wsel[idx]*GW[idx]; }
  __shared__ float sh4[4];
  float r = block_reduce(s, sh4);
  if(t==0) trp[which*64 + blockIdx.y] = r;
}

__global__ void finalize_scalars(const float* __restrict__ trp, const float* __restrict__ bq,
                                 const float* __restrict__ bk, const float* __restrict__ avec,
                                 float* __restrict__ ksum, float* __restrict__ scal){
  __shared__ float sh4[4];
  int t=threadIdx.x;
  float pq = (t<64)? trp[t]    : 0.f;
  float pk = (t<64)? trp[64+t] : 0.f;
  float bqaq=0.f,bkak=0.f,bq2=0.f,bk2=0.f;
  #pragma unroll
  for(int p=0;p<4;p++){ int jn=t+p*256;
    float qv=bq[jn], kv=bk[jn];
    bqaq += qv*avec[jn]; bkak += kv*avec[1024+jn];
    bq2 += qv*qv; bk2 += kv*kv; }
  float tq = block_reduce(pq, sh4);
  float tk = block_reduce(pk, sh4);
  float s1 = block_reduce(bqaq, sh4);
  float s2 = block_reduce(bkak, sh4);
  float s3 = block_reduce(bq2, sh4);
  float s4 = block_reduce(bk2, sh4);
  if(t==0){
    float q2 = tq + 2.f*s1 + FN*s3;
    float k2 = tk + 2.f*s2 + FN*s4;
    scal[0] = rsqrtf(q2)*rsqrtf(k2);
  }
  #pragma unroll
  for(int p=0;p<4;p++){ int jn=t+p*256; ksum[jn] = avec[1024+jn] + FN*bk[jn]; }
}

// ---------------- kvs ------------------------------------------------------
__global__ void kvs_k(const float* __restrict__ Wk, const float* __restrict__ GWv,
                      const float* __restrict__ avec, const float* __restrict__ bk,
                      const float* __restrict__ bv, float* __restrict__ kvs){
  int hh=blockIdx.x, tile=blockIdx.y;
  int m0=(tile>>2)*64, d0=(tile&3)*64;
  __shared__ float As[32][64], Bs[32][64];
  int t=threadIdx.x, tn=t&15, tm=t>>4;
  float acc[4][4]={};
  for(int k0=0;k0<256;k0+=32){
    int kr=t>>6, cc=t&63;
    #pragma unroll
    for(int p=0;p<8;p++){
      int k=kr+p*4;
      As[k][cc] = Wk [(size_t)(k0+k)*PJ + hh*256 + m0+cc];
      Bs[k][cc] = GWv[(size_t)(k0+k)*PJ + hh*256 + d0+cc];
    }
    __syncthreads();
    for(int k=0;k<32;k++){
      float a[4], b[4];
      #pragma unroll
      for(int i=0;i<4;i++) a[i]=As[k][tm*4+i];
      #pragma unroll
      for(int j=0;j<4;j++) b[j]=Bs[k][tn*4+j];
      #pragma unroll
      for(int i=0;i<4;i++)
        #pragma unroll
        for(int j=0;j<4;j++) acc[i][j] += a[i]*b[j];
    }
    __syncthreads();
  }
  const float* ak = avec+1024; const float* av = avec+2048;
  #pragma unroll
  for(int i=0;i<4;i++)
    #pragma unroll
    for(int j=0;j<4;j++){
      int m=m0+tm*4+i, d=d0+tn*4+j;
      float akm=ak[hh*256+m], bkm=bk[hh*256+m];
      float avd=av[hh*256+d], bvd=bv[hh*256+d];
      kvs[(size_t)hh*65536 + m*256 + d] = acc[i][j] + akm*bvd + bkm*avd + FN*bkm*bvd;
    }
}

// -------- U = scale*Wq@kvs + N*Wv, written transposed bf16 -> Ut[1024][UTP]
__global__ void u_gemm(const float* __restrict__ Wq, const float* __restrict__ kvs,
                       const float* __restrict__ Wv, const float* __restrict__ scal,
                       unsigned short* __restrict__ Ut){
  int hh=blockIdx.x, tile=blockIdx.y;
  int i0=(tile>>2)*64, d0=(tile&3)*64;
  __shared__ float As[64][33]; __shared__ float Bs[32][64];
  __shared__ unsigned short ts[64][72];
  int t=threadIdx.x, tn=t&15, tm=t>>4;
  float acc[4][4]={};
  for(int k0=0;k0<256;k0+=32){
    { int kk=t&31, rr=t>>5;
      #pragma unroll
      for(int p=0;p<8;p++){ int r=rr+p*8;
        As[r][kk] = Wq[(size_t)(i0+r)*PJ + hh*256 + k0+kk]; } }
    { int kr=t>>6, cc=t&63;
      #pragma unroll
      for(int p=0;p<8;p++){ int k=kr+p*4;
        Bs[k][cc] = kvs[(size_t)hh*65536 + (k0+k)*256 + d0+cc]; } }
    __syncthreads();
    for(int k=0;k<32;k++){
      float a[4], b[4];
      #pragma unroll
      for(int i=0;i<4;i++) a[i]=As[tm*4+i][k];
      #pragma unroll
      for(int j=0;j<4;j++) b[j]=Bs[k][tn*4+j];
      #pragma unroll
      for(int i=0;i<4;i++)
        #pragma unroll
        for(int j=0;j<4;j++) acc[i][j] += a[i]*b[j];
    }
    __syncthreads();
  }
  float sc = scal[0];
  #pragma unroll
  for(int i=0;i<4;i++)
    #pragma unroll
    for(int j=0;j<4;j++){
      int ii=i0+tm*4+i, d=d0+tn*4+j;
      float val = sc*acc[i][j] + FN*Wv[(size_t)ii*PJ + hh*256 + d];
      ts[tn*4+j][tm*4+i] = f2bf(val);
    }
  __syncthreads();
  { int ld = t>>2, q = t&3;
    unsigned short tmp[16];
    #pragma unroll
    for(int i=0;i<16;i++) tmp[i]=ts[ld][q*16+i];
    unsigned short* dst = Ut + (size_t)(hh*256+d0+ld)*UTP + i0 + q*16;
    *(u16x8*)(dst)   = *(u16x8*)&tmp[0];
    *(u16x8*)(dst+8) = *(u16x8*)&tmp[8];
  }
}

// ---------------- per-head vectors -----------------------------------------
__global__ void head_vecs(const float* __restrict__ Wq, const float* __restrict__ bq,
                          const float* __restrict__ bv, const float* __restrict__ kvs,
                          const float* __restrict__ ksum, const float* __restrict__ scal,
                          float* __restrict__ uvec, float* __restrict__ wvec,
                          float* __restrict__ cvec){
  int hh=blockIdx.x, t=threadIdx.x;
  float scale=scal[0];
  __shared__ float bqs[256], kss[256];
  __shared__ float sh4[4];
  bqs[t]=bq[hh*256+t]; kss[t]=ksum[hh*256+t];
  __syncthreads();
  float su=0.f;
  for(int m=0;m<256;m++) su += bqs[m]*kvs[(size_t)hh*65536 + m*256 + t];
  uvec[hh*256+t] = scale*su + FN*bv[hh*256+t];
  float sw=0.f;
  for(int m=0;m<256;m++) sw += Wq[(size_t)t*PJ + hh*256 + m]*kss[m];
  wvec[hh*256+t] = scale*sw;
  float pc = bqs[t]*kss[t];
  float total = block_reduce(pc, sh4);
  if(t==0) cvec[hh] = scale*total + FN;
}

// ---------------- denom (reciprocal), bf16 h input -------------------------
__global__ void denom_k(const unsigned short* __restrict__ hb, const float* __restrict__ wvec,
                        const float* __restrict__ cvec, float* __restrict__ denom, int M){
  __shared__ float wvl[1024];
  for(int i=threadIdx.x;i<1024;i+=256) wvl[i]=wvec[i];
  __syncthreads();
  int lane=threadIdx.x&63, wv=threadIdx.x>>6;
  int row=blockIdx.x*4+wv;
  if(row>=M) return;
  ushort4 hv = *(const ushort4*)(hb + (size_t)row*HID + lane*4);
  float h0=bf2f(hv.x), h1=bf2f(hv.y), h2=bf2f(hv.z), h3=bf2f(hv.w);
  float p[4];
  #pragma unroll
  for(int hh=0;hh<4;hh++){
    const float* wl = wvl + hh*256 + lane*4;
    p[hh] = h0*wl[0] + h1*wl[1] + h2*wl[2] + h3*wl[3];
  }
  #pragma unroll
  for(int hh=0;hh<4;hh++) p[hh]=wave_reduce(p[hh]);
  if(lane==0){
    #pragma unroll
    for(int hh=0;hh<4;hh++) denom[(size_t)row*4+hh] = 1.0f/(p[hh]+cvec[hh]);
  }
}

// ---------------- attn v2: 32x32x16, head-split waves, LDS head-reduce -----
// 512 thr, BM=128, col strip 64 (grid y=4); wave (wr,wc=head) = 64x64 tile
__global__ __launch_bounds__(512)
void attn_mfma(const unsigned short* __restrict__ hb, const unsigned short* __restrict__ Ut,
               const float* __restrict__ uvec, const float* __restrict__ rden,
               float* __restrict__ outp){
  __shared__ __align__(16) unsigned char smem[57344];
  unsigned short (*as)[72] = (unsigned short(*)[72])smem;            // 128x72
  unsigned short (*bs)[72] = (unsigned short(*)[72])(smem + 18432);  // 256x72
  float (*rsh)[4] = (float(*)[4])(smem + 55296);                     // 128x4
  float (*red)[64] = (float(*)[64])(smem + 18432);                   // overlay bs
  int bm = blockIdx.x*128;
  int c0 = blockIdx.y*64;
  int t = threadIdx.x, w = t>>6, lane = t&63;
  int wr = w>>2, wc = w&3;   // wc = head
  f32x16 acc[2][2];
  #pragma unroll
  for(int i=0;i<2;i++)
    #pragma unroll
    for(int j=0;j<2;j++)
      #pragma unroll
      for(int e=0;e<16;e++) acc[i][j][e] = 0.f;

  for(int k0=0;k0<HID;k0+=64){
    { int r = t>>2, q = t&3;
      const unsigned short* src = hb + (size_t)(bm+r)*HID + k0 + q*16;
      u16x8 v0={0,0,0,0,0,0,0,0}, v1={0,0,0,0,0,0,0,0};
      if(bm+r<NN){ v0=*(const u16x8*)src; v1=*(const u16x8*)(src+8); }
      *(u16x8*)&as[r][q*16] = v0; *(u16x8*)&as[r][q*16+8] = v1;
    }
    { int n = t&255, half = t>>8;
      int gn = (n>>6)*256 + c0 + (n&63);
      const unsigned short* src = Ut + (size_t)gn*UTP + k0 + half*32;
      #pragma unroll
      for(int i=0;i<4;i++) *(u16x8*)&bs[n][half*32 + i*8] = *(const u16x8*)(src + i*8);
    }
    __syncthreads();
    #pragma unroll
    for(int ks=0;ks<4;ks++){
      int kc = ks*16 + (lane>>5)*8;
      i32x4 a0 = *(const i32x4*)&as[wr*64 +      (lane&31)][kc];
      i32x4 a1 = *(const i32x4*)&as[wr*64 + 32 + (lane&31)][kc];
      i32x4 b0 = *(const i32x4*)&bs[wc*64 +      (lane&31)][kc];
      i32x4 b1 = *(const i32x4*)&bs[wc*64 + 32 + (lane&31)][kc];
      mfma32(acc[0][0], a0, b0); mfma32(acc[0][1], a0, b1);
      mfma32(acc[1][0], a1, b0); mfma32(acc[1][1], a1, b1);
    }
    __syncthreads();
  }
  // stage reciprocal denoms
  { int r = t>>2, h2 = t&3;
    rsh[r][h2] = (bm+r<NN) ? rden[(size_t)(bm+r)*4 + h2] : 0.f; }
  float uv[2];
  uv[0] = uvec[wc*256 + c0 +      (lane&31)];
  uv[1] = uvec[wc*256 + c0 + 32 + (lane&31)];
  __syncthreads();
  // head reduction into red[128][64]
  #pragma unroll
  for(int h=0;h<4;h++){
    if(wc==h){
      #pragma unroll
      for(int ti=0;ti<2;ti++)
        #pragma unroll
        for(int tj=0;tj<2;tj++)
          #pragma unroll
          for(int rg=0;rg<16;rg++){
            int rl = wr*64 + ti*32 + (rg&3) + ((rg>>2)<<3) + ((lane>>5)<<2);
            int cl = tj*32 + (lane&31);
            float v = (acc[ti][tj][rg] + uv[tj]) * rsh[rl][wc] * 0.25f;
            if(h==0) red[rl][cl] = v; else red[rl][cl] += v;
          }
    }
    __syncthreads();
  }
  // final: add residual, write fp32
  { int r = t>>2, cb4 = (t&3)*16;
    int gr = bm + r;
    if(gr < NN){
      const unsigned short* hres = hb + (size_t)gr*HID + c0 + cb4;
      float* dst = outp + (size_t)gr*HID + c0 + cb4;
      #pragma unroll
      for(int e=0;e<16;e++)
        dst[e] = (red[r][cb4+e] + bf2f(hres[e])) * 0.5f;
    }
  }
}

extern "C" void kernel_launch(void* const* d_in, const int* in_sizes, int n_in,
                              void* d_out, int out_size, void* d_ws, size_t ws_size,
                              hipStream_t stream){
  const float* x    = (const float*)d_in[0];
  const float* fc_w = (const float*)d_in[1];
  const float* fc_b = (const float*)d_in[2];
  const float* ln0g = (const float*)d_in[3];
  const float* ln0b = (const float*)d_in[4];
  float* out = (float*)d_out;

  float* W = (float*)d_ws;
  size_t o=0;
  float* buf1 = W+o; o+=(size_t)NN*HID;                              // hpre fp32
  unsigned short* hb  = (unsigned short*)(W+o); o+=(size_t)NN*HID/2;
  unsigned short* ht  = (unsigned short*)(W+o); o+=(size_t)HID*KTP/2;
  unsigned short* FWT = (unsigned short*)(W+o); o+=(size_t)HID*FWP/2 + 8;
  unsigned short* Ut  = (unsigned short*)(W+o); o+=(size_t)PJ*UTP/2 + 8;
  float* gramp= W+o; o+=(size_t)4*NCH*16384;
  float* G    = W+o; o+=65536;
  float* gw   = W+o; o+=3*262144;
  float* svec = W+o; o+=256;
  float* avec = W+o; o+=3072;
  float* trp  = W+o; o+=128;
  float* scal = W+o; o+=16;
  float* ksum = W+o; o+=1024;
  float* kvs  = W+o; o+=262144;
  float* uvec = W+o; o+=1024;
  float* wvec = W+o; o+=1024;
  float* cvec = W+o; o+=8;
  float* denB = W+o; o+=(size_t)NN*4;
  (void)ws_size; (void)in_sizes; (void)n_in; (void)out_size;

  dim3 blk(256);
  wconv<<<dim3(512),blk,0,stream>>>(fc_w, FWT);
  ffn_gemm<<<dim3(391),dim3(512),0,stream>>>(x, FWT, fc_b, ln0g, ln0b, hb);

  for(int L=0; L<2; L++){
    const float* wq = (const float*)d_in[5+L*8+0];
    const float* bq = (const float*)d_in[5+L*8+1];
    const float* wk = (const float*)d_in[5+L*8+2];
    const float* bk = (const float*)d_in[5+L*8+3];
    const float* wv = (const float*)d_in[5+L*8+4];
    const float* bv = (const float*)d_in[5+L*8+5];
    const float* lng= (const float*)d_in[5+L*8+6];
    const float* lnb= (const float*)d_in[5+L*8+7];

    transpose_h<<<dim3(784,4),blk,0,stream>>>(hb, ht);
    gram_mfma<<<dim3(4,NCH),blk,0,stream>>>(ht, gramp);
    gram_reduce2<<<dim3(4,64),blk,0,stream>>>(gramp, G);
    rowsum_ht<<<dim3(256),blk,0,stream>>>(ht, svec);
    gw_gemm3<<<dim3(4,16,3),blk,0,stream>>>(G, wq, wk, wv, gw);
    wt_s<<<dim3(3,4),blk,0,stream>>>(wq,wk,wv,svec,avec);
    trace_partial<<<dim3(2,64),blk,0,stream>>>(wq,wk,gw,trp);
    finalize_scalars<<<dim3(1),blk,0,stream>>>(trp,bq,bk,avec,ksum,scal);
    kvs_k<<<dim3(4,16),blk,0,stream>>>(wk, gw+2*262144, avec, bk, bv, kvs);
    u_gemm<<<dim3(4,16),blk,0,stream>>>(wq, kvs, wv, scal, Ut);
    head_vecs<<<dim3(4),blk,0,stream>>>(wq,bq,bv,kvs,ksum,scal,uvec,wvec,cvec);
    denom_k<<<dim3(12500),blk,0,stream>>>(hb, wvec, cvec, denB, NN);
    attn_mfma<<<dim3(391,4),dim3(512),0,stream>>>(hb, Ut, uvec, denB, buf1);
    ln_relu2<<<dim3(12500),blk,0,stream>>>(buf1, lng, lnb,
                                           L ? (unsigned short*)nullptr : hb,
                                           L ? out : (float*)nullptr, NN);
  }
}

// Round 4
// 519.959 us; speedup vs baseline: 4.1458x; 1.1740x over previous
//
#include <hip/hip_runtime.h>

#define NN    50000
#define IN_CH 512
#define HID   256
#define PJ    1024
#define FN    50000.0f
#define KTP   50176          // padded node-dim for ht (784*64)
#define NCH   98
#define CHK   512

typedef __attribute__((ext_vector_type(4)))  float f32x4;
typedef __attribute__((ext_vector_type(16))) float f32x16;
typedef __attribute__((ext_vector_type(4)))  int   i32x4;
typedef __attribute__((ext_vector_type(8)))  unsigned short u16x8;

__device__ inline void mfma16(f32x4& c, i32x4 a, i32x4 b){
  asm("v_mfma_f32_16x16x32_bf16 %0, %1, %2, %0" : "+v"(c) : "v"(a), "v"(b));
}
__device__ inline void mfma32(f32x16& c, i32x4 a, i32x4 b){
  asm("v_mfma_f32_32x32x16_bf16 %0, %1, %2, %0" : "+v"(c) : "v"(a), "v"(b));
}

__device__ inline unsigned short f2bf(float f){
  unsigned int u = __builtin_bit_cast(unsigned int, f);
  unsigned int r = (u + 0x7fffu + ((u >> 16) & 1u)) >> 16;
  return (unsigned short)r;
}
__device__ inline float bf2f(unsigned short u){
  unsigned int x = ((unsigned int)u) << 16;
  return __builtin_bit_cast(float, x);
}

__device__ inline float wave_reduce(float v){
  #pragma unroll
  for(int o=32;o>0;o>>=1) v += __shfl_down(v,o,64);
  return v;
}
__device__ inline float block_reduce(float v, float* sh4){
  v = wave_reduce(v);
  int lane = threadIdx.x & 63, wv = threadIdx.x >> 6;
  if(lane==0) sh4[wv] = v;
  __syncthreads();
  float r = sh4[0]+sh4[1]+sh4[2]+sh4[3];
  __syncthreads();
  return r;
}

// ---- fc_w [512][256] fp32 -> FWT2 tiled bf16 [kb=8][256 n][64 k] ----------
__global__ void wconv(const float* __restrict__ w, unsigned short* __restrict__ wt){
  int idx = blockIdx.x*256 + threadIdx.x;
  if(idx >= IN_CH*HID) return;
  int k = idx >> 8, n = idx & 255;
  wt[((size_t)(k>>6)*256 + n)*64 + (k&63)] = f2bf(w[idx]);
}

// ---------------- FFN + fused LN + ReLU -> hb bf16 -------------------------
__global__ __launch_bounds__(512)
void ffn_gemm(const float* __restrict__ X, const unsigned short* __restrict__ FWT2,
              const float* __restrict__ bias, const float* __restrict__ g,
              const float* __restrict__ b2, unsigned short* __restrict__ hbo){
  __shared__ __align__(16) unsigned char smem[55296];
  unsigned short (*as)[72] = (unsigned short(*)[72])smem;            // 128x72
  unsigned short (*bs)[72] = (unsigned short(*)[72])(smem + 18432);  // 256x72
  int t = threadIdx.x;
  int bm = blockIdx.x*128;
  int w = t>>6, lane = t&63;
  int wr = w>>2, wc = w&3;
  f32x4 acc[4][4];
  #pragma unroll
  for(int i=0;i<4;i++)
    #pragma unroll
    for(int j=0;j<4;j++) acc[i][j] = (f32x4){0.f,0.f,0.f,0.f};

  for(int k0=0;k0<IN_CH;k0+=64){
    { int r = t>>2, q = t&3;
      const float* src = X + (size_t)(bm+r)*IN_CH + k0 + q*16;
      bool ok = (bm+r) < NN;
      #pragma unroll
      for(int i=0;i<4;i++){
        float4 v = ok ? *(const float4*)(src + i*4) : make_float4(0.f,0.f,0.f,0.f);
        ushort4 u; u.x=f2bf(v.x); u.y=f2bf(v.y); u.z=f2bf(v.z); u.w=f2bf(v.w);
        *(ushort4*)&as[r][q*16 + i*4] = u;
      }
    }
    { int n = t>>1, q = t&1;   // dense tiled source: 64 B per thread
      const unsigned short* src = FWT2 + (size_t)(k0>>6)*16384 + (size_t)t*32;
      #pragma unroll
      for(int i=0;i<4;i++)
        *(u16x8*)&bs[n][q*32 + i*8] = *(const u16x8*)(src + i*8);
    }
    __syncthreads();
    #pragma unroll
    for(int ks=0;ks<2;ks++){
      i32x4 af[4], bfv[4];
      #pragma unroll
      for(int i=0;i<4;i++) af[i]  = *(const i32x4*)&as[wr*64 + i*16 + (lane&15)][ks*32 + (lane>>4)*8];
      #pragma unroll
      for(int j=0;j<4;j++) bfv[j] = *(const i32x4*)&bs[wc*64 + j*16 + (lane&15)][ks*32 + (lane>>4)*8];
      #pragma unroll
      for(int i=0;i<4;i++)
        #pragma unroll
        for(int j=0;j<4;j++) mfma16(acc[i][j], af[i], bfv[j]);
    }
    __syncthreads();
  }
  int cb = wc*64;
  #pragma unroll
  for(int j=0;j<4;j++){
    float bb = bias[cb + j*16 + (lane&15)];
    #pragma unroll
    for(int i=0;i<4;i++)
      #pragma unroll
      for(int r=0;r<4;r++) acc[i][j][r] += bb;
  }
  float (*lnp)[4][2] = (float(*)[4][2])smem;
  float (*lnstat)[2] = (float(*)[2])(smem + 4096);
  #pragma unroll
  for(int i=0;i<4;i++)
    #pragma unroll
    for(int r=0;r<4;r++){
      float s=0.f, q=0.f;
      #pragma unroll
      for(int j=0;j<4;j++){ float a=acc[i][j][r]; s+=a; q+=a*a; }
      #pragma unroll
      for(int m=1;m<16;m<<=1){ s += __shfl_xor(s,m,64); q += __shfl_xor(q,m,64); }
      if((lane&15)==0){
        int row = wr*64 + i*16 + (lane>>4)*4 + r;
        lnp[row][wc][0]=s; lnp[row][wc][1]=q;
      }
    }
  __syncthreads();
  if(t<128){
    float s=0.f,q=0.f;
    #pragma unroll
    for(int c=0;c<4;c++){ s+=lnp[t][c][0]; q+=lnp[t][c][1]; }
    float mu = s*(1.f/HID);
    float var = q*(1.f/HID) - mu*mu;
    lnstat[t][0]=mu; lnstat[t][1]=rsqrtf(var+1e-5f);
  }
  __syncthreads();
  #pragma unroll
  for(int j=0;j<4;j++){
    int col = cb + j*16 + (lane&15);
    float gg = g[col], bb = b2[col];
    #pragma unroll
    for(int i=0;i<4;i++)
      #pragma unroll
      for(int r=0;r<4;r++){
        int row = wr*64 + i*16 + (lane>>4)*4 + r;
        int grow = bm + row;
        if(grow<NN){
          float y = fmaxf((acc[i][j][r]-lnstat[row][0])*lnstat[row][1]*gg + bb, 0.f);
          hbo[(size_t)grow*HID + col] = f2bf(y);
        }
      }
  }
}

// ---------------- LN+ReLU (post-attn): fp32 in -> bf16 and/or fp32 out -----
__global__ void ln_relu2(const float* __restrict__ in, const float* __restrict__ g,
                         const float* __restrict__ b, unsigned short* __restrict__ outb,
                         float* __restrict__ outf, int M){
  int lane = threadIdx.x & 63, wv = threadIdx.x >> 6;
  int row = blockIdx.x*4 + wv;
  if(row>=M) return;
  const float* r = in + (size_t)row*HID;
  float v[4], sum=0.f, sq=0.f;
  #pragma unroll
  for(int j=0;j<4;j++){ v[j]=r[lane+j*64]; sum+=v[j]; sq+=v[j]*v[j]; }
  sum = wave_reduce(sum); sq = wave_reduce(sq);
  sum = __shfl(sum,0,64); sq = __shfl(sq,0,64);
  float mu = sum*(1.f/HID);
  float var = sq*(1.f/HID) - mu*mu;
  float rs = rsqrtf(var + 1e-5f);
  #pragma unroll
  for(int j=0;j<4;j++){ int c=lane+j*64;
    float y = fmaxf((v[j]-mu)*rs*g[c] + b[c], 0.f);
    if(outb) outb[(size_t)row*HID + c] = f2bf(y);
    if(outf) outf[(size_t)row*HID + c] = y;
  }
}

// ---------------- hb [NN][256] bf16 -> ht [256][KTP] bf16 (zero-padded) ----
__global__ __launch_bounds__(256)
void transpose_h(const unsigned short* __restrict__ hb, unsigned short* __restrict__ ht){
  __shared__ unsigned short ts[64][72];
  int r0 = blockIdx.x*64, c0 = blockIdx.y*64;
  int t = threadIdx.x;
  { int r = t&63, q = t>>6;
    #pragma unroll
    for(int i=0;i<2;i++){
      int c = q*16 + i*8;
      u16x8 v = {0,0,0,0,0,0,0,0};
      if(r0+r < NN) v = *(const u16x8*)(hb + (size_t)(r0+r)*HID + c0 + c);
      *(u16x8*)&ts[r][c] = v;
    }
  }
  __syncthreads();
  { int c = t>>2, q = t&3;
    unsigned short tmp[16];
    #pragma unroll
    for(int i=0;i<16;i++) tmp[i] = ts[q*16+i][c];
    unsigned short* dst = ht + (size_t)(c0+c)*KTP + r0 + q*16;
    *(u16x8*)(dst)   = *(u16x8*)&tmp[0];
    *(u16x8*)(dst+8) = *(u16x8*)&tmp[8];
  }
}

// ---------------- G = h^T h via MFMA on ht, split-K partials ---------------
__global__ __launch_bounds__(256)
void gram_mfma(const unsigned short* __restrict__ ht, float* __restrict__ gp){
  __shared__ unsigned short as[128][72], bs[128][72];
  int q = blockIdx.x, ch = blockIdx.y;
  int r0 = (q>>1)*128, c0 = (q&1)*128;
  int t = threadIdx.x, w=t>>6, lane=t&63;
  int wr=w>>1, wc=w&1;
  f32x4 acc[4][4];
  #pragma unroll
  for(int i=0;i<4;i++)
    #pragma unroll
    for(int j=0;j<4;j++) acc[i][j] = (f32x4){0.f,0.f,0.f,0.f};
  size_t kbase = (size_t)ch*CHK;
  for(int k0=0;k0<CHK;k0+=64){
    { int r = t>>1, h2 = t&1;
      const unsigned short* srcA = ht + (size_t)(r0+r)*KTP + kbase + k0 + h2*32;
      const unsigned short* srcB = ht + (size_t)(c0+r)*KTP + kbase + k0 + h2*32;
      #pragma unroll
      for(int i=0;i<4;i++) *(u16x8*)&as[r][h2*32+i*8] = *(const u16x8*)(srcA + i*8);
      #pragma unroll
      for(int i=0;i<4;i++) *(u16x8*)&bs[r][h2*32+i*8] = *(const u16x8*)(srcB + i*8);
    }
    __syncthreads();
    #pragma unroll
    for(int ks=0;ks<2;ks++){
      i32x4 af[4], bfv[4];
      #pragma unroll
      for(int i=0;i<4;i++) af[i]  = *(const i32x4*)&as[wr*64 + i*16 + (lane&15)][ks*32 + (lane>>4)*8];
      #pragma unroll
      for(int j=0;j<4;j++) bfv[j] = *(const i32x4*)&bs[wc*64 + j*16 + (lane&15)][ks*32 + (lane>>4)*8];
      #pragma unroll
      for(int i=0;i<4;i++)
        #pragma unroll
        for(int j=0;j<4;j++) mfma16(acc[i][j], af[i], bfv[j]);
    }
    __syncthreads();
  }
  float* dst = gp + ((size_t)q*NCH + ch)*16384;
  #pragma unroll
  for(int i=0;i<4;i++)
    #pragma unroll
    for(int j=0;j<4;j++)
      #pragma unroll
      for(int r=0;r<4;r++)
        dst[(wr*64+i*16+(lane>>4)*4+r)*128 + wc*64+j*16+(lane&15)] = acc[i][j][r];
}

__global__ void gram_reduce2(const float* __restrict__ gp, float* __restrict__ G){
  int q=blockIdx.x; int e = blockIdx.y*256 + threadIdx.x;
  const float* p = gp + (size_t)q*NCH*16384 + e;
  float s=0.f;
  for(int c=0;c<NCH;c++) s += p[(size_t)c*16384];
  int i = e>>7, j = e&127;
  int r0=(q>>1)*128, c0=(q&1)*128;
  G[(r0+i)*256 + c0+j] = s;
}

// ---------------- svec[col] = sum_n h[n][col]  (row-sums of ht) ------------
__global__ void rowsum_ht(const unsigned short* __restrict__ ht, float* __restrict__ svec){
  int row = blockIdx.x;
  const unsigned short* p = ht + (size_t)row*KTP;
  float s = 0.f;
  for(int i = threadIdx.x*8; i < KTP; i += 2048){
    u16x8 v = *(const u16x8*)(p + i);
    #pragma unroll
    for(int e=0;e<8;e++) s += bf2f(v[e]);
  }
  __shared__ float sh4[4];
  float tot = block_reduce(s, sh4);
  if(threadIdx.x==0) svec[row] = tot;
}

// ---------------- gw_z = G @ W_z (z=0,1,2) fp32 ----------------------------
__global__ void gw_gemm3(const float* __restrict__ G, const float* __restrict__ Wq,
                         const float* __restrict__ Wk, const float* __restrict__ Wv,
                         float* __restrict__ gw){
  const float* B = blockIdx.z==0?Wq:(blockIdx.z==1?Wk:Wv);
  float* C = gw + (size_t)blockIdx.z*262144;
  __shared__ float As[64][33];
  __shared__ float Bs[32][64];
  int bm = blockIdx.x*64, bn = blockIdx.y*64;
  int t = threadIdx.x;
  int tn = t & 15, tm = t >> 4;
  float acc[4][4] = {};
  for(int k0=0;k0<HID;k0+=32){
    { int kk=t&31, rr=t>>5;
      #pragma unroll
      for(int p=0;p<8;p++){ int r=rr+p*8;
        As[r][kk] = G[(size_t)(bm+r)*HID + k0+kk]; } }
    { int nn=t&63, kr=t>>6;
      #pragma unroll
      for(int p=0;p<8;p++){ int k=kr+p*4;
        Bs[k][nn] = B[(size_t)(k0+k)*PJ + bn+nn]; } }
    __syncthreads();
    for(int k=0;k<32;k++){
      float a[4], b[4];
      #pragma unroll
      for(int i=0;i<4;i++) a[i]=As[tm*4+i][k];
      #pragma unroll
      for(int j=0;j<4;j++) b[j]=Bs[k][tn*4+j];
      #pragma unroll
      for(int i=0;i<4;i++)
        #pragma unroll
        for(int j=0;j<4;j++) acc[i][j] += a[i]*b[j];
    }
    __syncthreads();
  }
  #pragma unroll
  for(int i=0;i<4;i++)
    #pragma unroll
    for(int j=0;j<4;j++)
      C[(size_t)(bm+tm*4+i)*PJ + bn+tn*4+j] = acc[i][j];
}

// ---------------- a{q,k,v} = W^T s -----------------------------------------
__global__ void wt_s(const float* __restrict__ Wq, const float* __restrict__ Wk,
                     const float* __restrict__ Wv, const float* __restrict__ s,
                     float* __restrict__ avec){
  const float* Wsel = (blockIdx.x==0)?Wq:(blockIdx.x==1)?Wk:Wv;
  int col = blockIdx.y*256 + threadIdx.x;
  __shared__ float ss[256];
  ss[threadIdx.x]=s[threadIdx.x];
  __syncthreads();
  float acc=0.f;
  for(int i=0;i<256;i++) acc += Wsel[(size_t)i*PJ + col]*ss[i];
  avec[blockIdx.x*1024 + col]=acc;
}

// ---------------- trace terms ----------------------------------------------
__global__ void trace_partial(const float* __restrict__ Wq, const float* __restrict__ Wk,
                              const float* __restrict__ gw, float* __restrict__ trp){
  int which = blockIdx.x;
  const float* Wsel = which ? Wk : Wq;
  const float* GW = gw + (size_t)which*262144;
  int t=threadIdx.x;
  int base = blockIdx.y*4096 + t;
  float s=0.f;
  #pragma unroll
  for(int i=0;i<16;i++){ int idx=base+i*256; s += Wsel[idx]*GW[idx]; }
  __shared__ float sh4[4];
  float r = block_reduce(s, sh4);
  if(t==0) trp[which*64 + blockIdx.y] = r;
}

__global__ void finalize_scalars(const float* __restrict__ trp, const float* __restrict__ bq,
                                 const float* __restrict__ bk, const float* __restrict__ avec,
                                 float* __restrict__ ksum, float* __restrict__ scal){
  __shared__ float sh4[4];
  int t=threadIdx.x;
  float pq = (t<64)? trp[t]    : 0.f;
  float pk = (t<64)? trp[64+t] : 0.f;
  float bqaq=0.f,bkak=0.f,bq2=0.f,bk2=0.f;
  #pragma unroll
  for(int p=0;p<4;p++){ int jn=t+p*256;
    float qv=bq[jn], kv=bk[jn];
    bqaq += qv*avec[jn]; bkak += kv*avec[1024+jn];
    bq2 += qv*qv; bk2 += kv*kv; }
  float tq = block_reduce(pq, sh4);
  float tk = block_reduce(pk, sh4);
  float s1 = block_reduce(bqaq, sh4);
  float s2 = block_reduce(bkak, sh4);
  float s3 = block_reduce(bq2, sh4);
  float s4 = block_reduce(bk2, sh4);
  if(t==0){
    float q2 = tq + 2.f*s1 + FN*s3;
    float k2 = tk + 2.f*s2 + FN*s4;
    scal[0] = rsqrtf(q2)*rsqrtf(k2);
  }
  #pragma unroll
  for(int p=0;p<4;p++){ int jn=t+p*256; ksum[jn] = avec[1024+jn] + FN*bk[jn]; }
}

// ---------------- kvs ------------------------------------------------------
__global__ void kvs_k(const float* __restrict__ Wk, const float* __restrict__ GWv,
                      const float* __restrict__ avec, const float* __restrict__ bk,
                      const float* __restrict__ bv, float* __restrict__ kvs){
  int hh=blockIdx.x, tile=blockIdx.y;
  int m0=(tile>>2)*64, d0=(tile&3)*64;
  __shared__ float As[32][64], Bs[32][64];
  int t=threadIdx.x, tn=t&15, tm=t>>4;
  float acc[4][4]={};
  for(int k0=0;k0<256;k0+=32){
    int kr=t>>6, cc=t&63;
    #pragma unroll
    for(int p=0;p<8;p++){
      int k=kr+p*4;
      As[k][cc] = Wk [(size_t)(k0+k)*PJ + hh*256 + m0+cc];
      Bs[k][cc] = GWv[(size_t)(k0+k)*PJ + hh*256 + d0+cc];
    }
    __syncthreads();
    for(int k=0;k<32;k++){
      float a[4], b[4];
      #pragma unroll
      for(int i=0;i<4;i++) a[i]=As[k][tm*4+i];
      #pragma unroll
      for(int j=0;j<4;j++) b[j]=Bs[k][tn*4+j];
      #pragma unroll
      for(int i=0;i<4;i++)
        #pragma unroll
        for(int j=0;j<4;j++) acc[i][j] += a[i]*b[j];
    }
    __syncthreads();
  }
  const float* ak = avec+1024; const float* av = avec+2048;
  #pragma unroll
  for(int i=0;i<4;i++)
    #pragma unroll
    for(int j=0;j<4;j++){
      int m=m0+tm*4+i, d=d0+tn*4+j;
      float akm=ak[hh*256+m], bkm=bk[hh*256+m];
      float avd=av[hh*256+d], bvd=bv[hh*256+d];
      kvs[(size_t)hh*65536 + m*256 + d] = acc[i][j] + akm*bvd + bkm*avd + FN*bkm*bvd;
    }
}

// -------- U = scale*Wq@kvs + N*Wv, written TILED bf16:
// Ut2[(s*4+kb)*16384 + (hh*64+dc)*64 + kk], s=d>>6, dc=d&63, kb=ii>>6, kk=ii&63
__global__ void u_gemm(const float* __restrict__ Wq, const float* __restrict__ kvs,
                       const float* __restrict__ Wv, const float* __restrict__ scal,
                       unsigned short* __restrict__ Ut2){
  int hh=blockIdx.x, tile=blockIdx.y;
  int i0=(tile>>2)*64, d0=(tile&3)*64;
  __shared__ float As[64][33]; __shared__ float Bs[32][64];
  int t=threadIdx.x, tn=t&15, tm=t>>4;
  float acc[4][4]={};
  for(int k0=0;k0<256;k0+=32){
    { int kk=t&31, rr=t>>5;
      #pragma unroll
      for(int p=0;p<8;p++){ int r=rr+p*8;
        As[r][kk] = Wq[(size_t)(i0+r)*PJ + hh*256 + k0+kk]; } }
    { int kr=t>>6, cc=t&63;
      #pragma unroll
      for(int p=0;p<8;p++){ int k=kr+p*4;
        Bs[k][cc] = kvs[(size_t)hh*65536 + (k0+k)*256 + d0+cc]; } }
    __syncthreads();
    for(int k=0;k<32;k++){
      float a[4], b[4];
      #pragma unroll
      for(int i=0;i<4;i++) a[i]=As[tm*4+i][k];
      #pragma unroll
      for(int j=0;j<4;j++) b[j]=Bs[k][tn*4+j];
      #pragma unroll
      for(int i=0;i<4;i++)
        #pragma unroll
        for(int j=0;j<4;j++) acc[i][j] += a[i]*b[j];
    }
    __syncthreads();
  }
  float sc = scal[0];
  #pragma unroll
  for(int i=0;i<4;i++)
    #pragma unroll
    for(int j=0;j<4;j++){
      int ii=i0+tm*4+i, d=d0+tn*4+j;
      float val = sc*acc[i][j] + FN*Wv[(size_t)ii*PJ + hh*256 + d];
      Ut2[((size_t)(d>>6)*4 + (ii>>6))*16384 + ((size_t)hh*64 + (d&63))*64 + (ii&63)] = f2bf(val);
    }
}

// ---------------- per-head vectors -----------------------------------------
__global__ void head_vecs(const float* __restrict__ Wq, const float* __restrict__ bq,
                          const float* __restrict__ bv, const float* __restrict__ kvs,
                          const float* __restrict__ ksum, const float* __restrict__ scal,
                          float* __restrict__ uvec, float* __restrict__ wvec,
                          float* __restrict__ cvec){
  int hh=blockIdx.x, t=threadIdx.x;
  float scale=scal[0];
  __shared__ float bqs[256], kss[256];
  __shared__ float sh4[4];
  bqs[t]=bq[hh*256+t]; kss[t]=ksum[hh*256+t];
  __syncthreads();
  float su=0.f;
  for(int m=0;m<256;m++) su += bqs[m]*kvs[(size_t)hh*65536 + m*256 + t];
  uvec[hh*256+t] = scale*su + FN*bv[hh*256+t];
  float sw=0.f;
  for(int m=0;m<256;m++) sw += Wq[(size_t)t*PJ + hh*256 + m]*kss[m];
  wvec[hh*256+t] = scale*sw;
  float pc = bqs[t]*kss[t];
  float total = block_reduce(pc, sh4);
  if(t==0) cvec[hh] = scale*total + FN;
}

// ---------------- denom (reciprocal), bf16 h input -------------------------
__global__ void denom_k(const unsigned short* __restrict__ hb, const float* __restrict__ wvec,
                        const float* __restrict__ cvec, float* __restrict__ denom, int M){
  __shared__ float wvl[1024];
  for(int i=threadIdx.x;i<1024;i+=256) wvl[i]=wvec[i];
  __syncthreads();
  int lane=threadIdx.x&63, wv=threadIdx.x>>6;
  int row=blockIdx.x*4+wv;
  if(row>=M) return;
  ushort4 hv = *(const ushort4*)(hb + (size_t)row*HID + lane*4);
  float h0=bf2f(hv.x), h1=bf2f(hv.y), h2=bf2f(hv.z), h3=bf2f(hv.w);
  float p[4];
  #pragma unroll
  for(int hh=0;hh<4;hh++){
    const float* wl = wvl + hh*256 + lane*4;
    p[hh] = h0*wl[0] + h1*wl[1] + h2*wl[2] + h3*wl[3];
  }
  #pragma unroll
  for(int hh=0;hh<4;hh++) p[hh]=wave_reduce(p[hh]);
  if(lane==0){
    #pragma unroll
    for(int hh=0;hh<4;hh++) denom[(size_t)row*4+hh] = 1.0f/(p[hh]+cvec[hh]);
  }
}

// ---------------- attn v3: BM=128, strip=256n (4 heads x 64), 8 waves 4x2 --
// A direct-from-global; B from tiled Ut2, dense staging + reg prefetch.
__global__ __launch_bounds__(512,4)
void attn_mfma(const unsigned short* __restrict__ hb, const unsigned short* __restrict__ Ut2,
               const float* __restrict__ uvec, const float* __restrict__ rden,
               float* __restrict__ outp){
  __shared__ __align__(16) unsigned char smem[38912];
  unsigned short (*bs)[72] = (unsigned short(*)[72])smem;   // 256 x 72 (36864 B)
  float (*red)[64] = (float(*)[64])smem;                    // overlay after loop
  float (*rsh)[4]  = (float(*)[4])(smem + 36864);           // 128 x 4
  int bm = blockIdx.x*128;
  int st = blockIdx.y;
  int t = threadIdx.x, w = t>>6, lane = t&63;
  int wr = w>>1, wc = w&1;
  int nst = t>>1, koff = (t&1)*32;

  f32x16 acc[4];
  #pragma unroll
  for(int j=0;j<4;j++)
    #pragma unroll
    for(int e=0;e<16;e++) acc[j][e]=0.f;

  { int r = t>>2, h2 = t&3;
    rsh[r][h2] = (bm+r<NN) ? rden[(size_t)(bm+r)*4+h2] : 1.0f; }

  const unsigned short* tb0 = Ut2 + (size_t)st*4*16384;
  u16x8 breg[4];
  #pragma unroll
  for(int i=0;i<4;i++) breg[i] = *(const u16x8*)(tb0 + (size_t)t*32 + i*8);

  int arow = bm + wr*32 + (lane&31); if(arow >= NN) arow = NN-1;
  const unsigned short* ap = hb + (size_t)arow*HID + (lane>>5)*8;

  #pragma unroll
  for(int kb=0;kb<4;kb++){
    __syncthreads();
    #pragma unroll
    for(int i=0;i<4;i++) *(u16x8*)&bs[nst][koff + i*8] = breg[i];
    __syncthreads();
    if(kb<3){
      const unsigned short* tn2 = Ut2 + ((size_t)st*4 + kb+1)*16384;
      #pragma unroll
      for(int i=0;i<4;i++) breg[i] = *(const u16x8*)(tn2 + (size_t)t*32 + i*8);
    }
    i32x4 a[4];
    #pragma unroll
    for(int ks=0;ks<4;ks++) a[ks] = *(const i32x4*)(ap + kb*64 + ks*16);
    #pragma unroll
    for(int ks=0;ks<4;ks++){
      int kc = ks*16 + (lane>>5)*8;
      #pragma unroll
      for(int j=0;j<4;j++){
        i32x4 b = *(const i32x4*)&bs[wc*128 + j*32 + (lane&31)][kc];
        mfma32(acc[j], a[ks], b);
      }
    }
  }
  // epilogue: in-lane 2-head sums; cross-wave pair (wc=1 -> wc=0) via LDS
  float uv[4];
  #pragma unroll
  for(int j=0;j<4;j++)
    uv[j] = uvec[(wc*2 + (j>>1))*256 + st*64 + (j&1)*32 + (lane&31)];
  __syncthreads();   // all bs reads done; safe to overlay red
  if(wc==1){
    #pragma unroll
    for(int r=0;r<16;r++){
      int row = wr*32 + (r&3) + ((r>>2)<<3) + ((lane>>5)<<2);
      float d0 = rsh[row][2], d1 = rsh[row][3];
      red[row][lane&31]      = (acc[0][r]+uv[0])*d0 + (acc[2][r]+uv[2])*d1;
      red[row][32+(lane&31)] = (acc[1][r]+uv[1])*d0 + (acc[3][r]+uv[3])*d1;
    }
  }
  __syncthreads();
  if(wc==0){
    #pragma unroll
    for(int r=0;r<16;r++){
      int row = wr*32 + (r&3) + ((r>>2)<<3) + ((lane>>5)<<2);
      int gr = bm + row;
      if(gr < NN){
        float d0 = rsh[row][0], d1 = rsh[row][1];
        float v0 = ((acc[0][r]+uv[0])*d0 + (acc[2][r]+uv[2])*d1 + red[row][lane&31])      * 0.25f;
        float v1 = ((acc[1][r]+uv[1])*d0 + (acc[3][r]+uv[3])*d1 + red[row][32+(lane&31)]) * 0.25f;
        const unsigned short* hres = hb + (size_t)gr*HID + st*64;
        float* dst = outp + (size_t)gr*HID + st*64;
        dst[lane&31]      = (v0 + bf2f(hres[lane&31])) * 0.5f;
        dst[32+(lane&31)] = (v1 + bf2f(hres[32+(lane&31)])) * 0.5f;
      }
    }
  }
}

extern "C" void kernel_launch(void* const* d_in, const int* in_sizes, int n_in,
                              void* d_out, int out_size, void* d_ws, size_t ws_size,
                              hipStream_t stream){
  const float* x    = (const float*)d_in[0];
  const float* fc_w = (const float*)d_in[1];
  const float* fc_b = (const float*)d_in[2];
  const float* ln0g = (const float*)d_in[3];
  const float* ln0b = (const float*)d_in[4];
  float* out = (float*)d_out;

  float* W = (float*)d_ws;
  size_t o=0;
  float* buf1 = W+o; o+=(size_t)NN*HID;
  unsigned short* hb   = (unsigned short*)(W+o); o+=(size_t)NN*HID/2;
  unsigned short* ht   = (unsigned short*)(W+o); o+=(size_t)HID*KTP/2;
  unsigned short* FWT2 = (unsigned short*)(W+o); o+=(size_t)8*16384/2 + 8;
  unsigned short* Ut2  = (unsigned short*)(W+o); o+=(size_t)16*16384/2 + 8;
  float* gramp= W+o; o+=(size_t)4*NCH*16384;
  float* G    = W+o; o+=65536;
  float* gw   = W+o; o+=3*262144;
  float* svec = W+o; o+=256;
  float* avec = W+o; o+=3072;
  float* trp  = W+o; o+=128;
  float* scal = W+o; o+=16;
  float* ksum = W+o; o+=1024;
  float* kvs  = W+o; o+=262144;
  float* uvec = W+o; o+=1024;
  float* wvec = W+o; o+=1024;
  float* cvec = W+o; o+=8;
  float* denB = W+o; o+=(size_t)NN*4;
  (void)ws_size; (void)in_sizes; (void)n_in; (void)out_size;

  dim3 blk(256);
  wconv<<<dim3(512),blk,0,stream>>>(fc_w, FWT2);
  ffn_gemm<<<dim3(391),dim3(512),0,stream>>>(x, FWT2, fc_b, ln0g, ln0b, hb);

  for(int L=0; L<2; L++){
    const float* wq = (const float*)d_in[5+L*8+0];
    const float* bq = (const float*)d_in[5+L*8+1];
    const float* wk = (const float*)d_in[5+L*8+2];
    const float* bk = (const float*)d_in[5+L*8+3];
    const float* wv = (const float*)d_in[5+L*8+4];
    const float* bv = (const float*)d_in[5+L*8+5];
    const float* lng= (const float*)d_in[5+L*8+6];
    const float* lnb= (const float*)d_in[5+L*8+7];

    transpose_h<<<dim3(784,4),blk,0,stream>>>(hb, ht);
    gram_mfma<<<dim3(4,NCH),blk,0,stream>>>(ht, gramp);
    gram_reduce2<<<dim3(4,64),blk,0,stream>>>(gramp, G);
    rowsum_ht<<<dim3(256),blk,0,stream>>>(ht, svec);
    gw_gemm3<<<dim3(4,16,3),blk,0,stream>>>(G, wq, wk, wv, gw);
    wt_s<<<dim3(3,4),blk,0,stream>>>(wq,wk,wv,svec,avec);
    trace_partial<<<dim3(2,64),blk,0,stream>>>(wq,wk,gw,trp);
    finalize_scalars<<<dim3(1),blk,0,stream>>>(trp,bq,bk,avec,ksum,scal);
    kvs_k<<<dim3(4,16),blk,0,stream>>>(wk, gw+2*262144, avec, bk, bv, kvs);
    u_gemm<<<dim3(4,16),blk,0,stream>>>(wq, kvs, wv, scal, Ut2);
    head_vecs<<<dim3(4),blk,0,stream>>>(wq,bq,bv,kvs,ksum,scal,uvec,wvec,cvec);
    denom_k<<<dim3(12500),blk,0,stream>>>(hb, wvec, cvec, denB, NN);
    attn_mfma<<<dim3(391,4),dim3(512),0,stream>>>(hb, Ut2, uvec, denB, buf1);
    ln_relu2<<<dim3(12500),blk,0,stream>>>(buf1, lng, lnb,
                                           L ? (unsigned short*)nullptr : hb,
                                           L ? out : (float*)nullptr, NN);
  }
}